// Round 1
// baseline (1959.313 us; speedup 1.0000x reference)
//
#include <hip/hip_runtime.h>

#define S 2048
#define H 1024
#define NH 16
#define NKV 8
#define HD 64
#define NE 8
#define ID 2048

typedef short bf16x8 __attribute__((ext_vector_type(8)));
typedef float f32x4 __attribute__((ext_vector_type(4)));

__device__ __forceinline__ unsigned short f2bf(float f) {
  unsigned u = __builtin_bit_cast(unsigned, f);
  u += 0x7FFFu + ((u >> 16) & 1u);
  return (unsigned short)(u >> 16);
}
__device__ __forceinline__ float bf2f(unsigned short h) {
  unsigned u = ((unsigned)h) << 16;
  return __builtin_bit_cast(float, u);
}

// ---------------- RMSNorm ----------------
__global__ __launch_bounds__(256) void rmsnorm_kernel(const float* __restrict__ x,
                                                      const float* __restrict__ w,
                                                      float* __restrict__ out) {
  int row = blockIdx.x;
  const float* xr = x + (size_t)row * H;
  int tid = threadIdx.x;
  float v[4];
  float ss = 0.f;
#pragma unroll
  for (int i = 0; i < 4; i++) {
    v[i] = xr[tid + i * 256];
    ss += v[i] * v[i];
  }
#pragma unroll
  for (int off = 1; off < 64; off <<= 1) ss += __shfl_xor(ss, off);
  __shared__ float part[4];
  if ((tid & 63) == 0) part[tid >> 6] = ss;
  __syncthreads();
  float tot = part[0] + part[1] + part[2] + part[3];
  float r = rsqrtf(tot * (1.f / H) + 1e-6f);
  float* orow = out + (size_t)row * H;
#pragma unroll
  for (int i = 0; i < 4; i++) {
    int c = tid + i * 256;
    orow[c] = v[i] * r * w[c];
  }
}

// ---------------- generic MFMA GEMM ----------------
// MODE 0: QKV  (A f32 [M][K], B f32 [K][N], split-bf16 x4, C f32)
// MODE 1: OPROJ (same + residual add)
// MODE 2: MOEA (A = gathered t rows f32, dual B = w1/w3 bf16, epilogue silu(g1)*g3 -> G bf16)
// MODE 3: MOEB (A = G bf16, B = w2 bf16, epilogue scaled atomicAdd into moe_acc)
#define BM 64
#define BN 64
#define BK 32

template <int MODE>
__global__ __launch_bounds__(256) void gemm_kernel(
    const float* __restrict__ A, const unsigned short* __restrict__ Abf,
    const float* __restrict__ Bw, const float* __restrict__ Bw2,
    float* __restrict__ C, unsigned short* __restrict__ Gout,
    const float* __restrict__ resid, const int* __restrict__ idx,
    const float* __restrict__ wgt, const int* __restrict__ cnt,
    const int* __restrict__ offs, int N, int K) {
  int nt = blockIdx.x, rt = blockIdx.y, e = blockIdx.z;
  int m0 = rt * BM, n0 = nt * BN;
  int ce = 0, gbase = 0;
  if (MODE >= 2) {
    ce = cnt[e];
    if (m0 >= ce) return;
    gbase = offs[e];
  }
  const float* B1 = Bw + (MODE >= 2 ? (size_t)e * H * ID : 0);
  const float* B2 = (MODE == 2) ? (Bw2 + (size_t)e * H * ID) : nullptr;

  __shared__ __align__(16) unsigned short Ahi[BM * BK];
  __shared__ __align__(16) unsigned short Alo[BM * BK];
  __shared__ __align__(16) unsigned short Bhi[BN * BK];
  __shared__ __align__(16) unsigned short Blo[BN * BK];
  __shared__ __align__(16) unsigned short B2hi[BN * BK];

  int tid = threadIdx.x;
  int ar = tid >> 2, ac = (tid & 3) * 8;
  int bk = tid >> 3, bn = (tid & 7) * 8;

  int atok = 0;
  if (MODE == 2) {
    int rr = m0 + ar;
    atok = (rr < ce) ? idx[e * S + rr] : 0;
  }
  int agrow = 0;
  if (MODE == 3) {
    agrow = gbase + m0 + ar;
    if (agrow > 4095) agrow = 4095;
  }

  int w = tid >> 6, lane = tid & 63;
  int wm = w >> 1, wn = w & 1;
  int lr = lane & 15, lk = (lane >> 4) * 8;

  f32x4 acc[2][2], acc2[2][2];
#pragma unroll
  for (int i = 0; i < 2; i++)
#pragma unroll
    for (int j = 0; j < 2; j++) {
      acc[i][j] = f32x4{0.f, 0.f, 0.f, 0.f};
      acc2[i][j] = f32x4{0.f, 0.f, 0.f, 0.f};
    }

  for (int k0 = 0; k0 < K; k0 += BK) {
    __syncthreads();
    // stage A
    {
      bf16x8 hv, lv;
      if (MODE == 3) {
        hv = *(const bf16x8*)(Abf + (size_t)agrow * K + k0 + ac);
      } else {
        const float* src;
        if (MODE == 2)
          src = A + (size_t)atok * H + k0 + ac;
        else
          src = A + (size_t)(m0 + ar) * K + k0 + ac;
#pragma unroll
        for (int i = 0; i < 8; i++) {
          float vv = src[i];
          unsigned short h_ = f2bf(vv);
          hv[i] = (short)h_;
          if (MODE <= 1) lv[i] = (short)f2bf(vv - bf2f(h_));
        }
      }
      *(bf16x8*)&Ahi[ar * BK + ac] = hv;
      if (MODE <= 1) *(bf16x8*)&Alo[ar * BK + ac] = lv;
    }
    // stage B transposed: LDS [n][k]
    {
      const float* src = B1 + (size_t)(k0 + bk) * N + n0 + bn;
#pragma unroll
      for (int j = 0; j < 8; j++) {
        float vv = src[j];
        unsigned short h_ = f2bf(vv);
        Bhi[(bn + j) * BK + bk] = h_;
        if (MODE <= 1) Blo[(bn + j) * BK + bk] = f2bf(vv - bf2f(h_));
      }
      if (MODE == 2) {
        const float* src2 = B2 + (size_t)(k0 + bk) * N + n0 + bn;
#pragma unroll
        for (int j = 0; j < 8; j++) B2hi[(bn + j) * BK + bk] = f2bf(src2[j]);
      }
    }
    __syncthreads();
    // compute
    bf16x8 ah[2], al[2], bh[2], bl[2], b2f[2];
#pragma unroll
    for (int i = 0; i < 2; i++) {
      ah[i] = *(bf16x8*)&Ahi[(wm * 32 + i * 16 + lr) * BK + lk];
      bh[i] = *(bf16x8*)&Bhi[(wn * 32 + i * 16 + lr) * BK + lk];
      if (MODE <= 1) {
        al[i] = *(bf16x8*)&Alo[(wm * 32 + i * 16 + lr) * BK + lk];
        bl[i] = *(bf16x8*)&Blo[(wn * 32 + i * 16 + lr) * BK + lk];
      }
      if (MODE == 2) b2f[i] = *(bf16x8*)&B2hi[(wn * 32 + i * 16 + lr) * BK + lk];
    }
#pragma unroll
    for (int i = 0; i < 2; i++)
#pragma unroll
      for (int j = 0; j < 2; j++) {
        acc[i][j] = __builtin_amdgcn_mfma_f32_16x16x32_bf16(ah[i], bh[j], acc[i][j], 0, 0, 0);
        if (MODE <= 1) {
          acc[i][j] = __builtin_amdgcn_mfma_f32_16x16x32_bf16(ah[i], bl[j], acc[i][j], 0, 0, 0);
          acc[i][j] = __builtin_amdgcn_mfma_f32_16x16x32_bf16(al[i], bh[j], acc[i][j], 0, 0, 0);
          acc[i][j] = __builtin_amdgcn_mfma_f32_16x16x32_bf16(al[i], bl[j], acc[i][j], 0, 0, 0);
        }
        if (MODE == 2)
          acc2[i][j] = __builtin_amdgcn_mfma_f32_16x16x32_bf16(ah[i], b2f[j], acc2[i][j], 0, 0, 0);
      }
  }
  // epilogue
#pragma unroll
  for (int i = 0; i < 2; i++)
#pragma unroll
    for (int j = 0; j < 2; j++)
#pragma unroll
      for (int r = 0; r < 4; r++) {
        int grow = wm * 32 + i * 16 + (lane >> 4) * 4 + r;
        int gcol = n0 + wn * 32 + j * 16 + lr;
        float v = acc[i][j][r];
        if (MODE == 0) {
          C[(size_t)(m0 + grow) * N + gcol] = v;
        } else if (MODE == 1) {
          C[(size_t)(m0 + grow) * N + gcol] = v + resid[(size_t)(m0 + grow) * N + gcol];
        } else if (MODE == 2) {
          if (m0 + grow < ce) {
            float g3 = acc2[i][j][r];
            float sg = v / (1.f + __expf(-v));
            Gout[(size_t)(gbase + m0 + grow) * ID + gcol] = f2bf(sg * g3);
          }
        } else {
          if (m0 + grow < ce) {
            int tok = idx[e * S + m0 + grow];
            float wv = wgt[e * S + m0 + grow];
            atomicAdd(&C[(size_t)tok * H + gcol], v * wv);
          }
        }
      }
}

// ---------------- RoPE ----------------
__global__ __launch_bounds__(256) void rope_kernel(
    const float* __restrict__ q, const float* __restrict__ k,
    const float* __restrict__ sinb, const float* __restrict__ cosb,
    const int* __restrict__ pos, float* __restrict__ qr, float* __restrict__ kr) {
  int i = blockIdx.x * 256 + threadIdx.x;
  int d = i & 31;
  int s = (i >> 5) & 2047;
  int hh = i >> 16;  // 32*2048 = 65536
  int p = pos[s];
  float c0 = cosb[p * HD + d], c1 = cosb[p * HD + d + 32];
  float s0 = sinb[p * HD + d], s1 = sinb[p * HD + d + 32];
  if (hh < NH) {
    const float* src = q + (size_t)s * (NH * HD) + hh * HD;
    float x0 = src[d], x1 = src[d + 32];
    float* dst = qr + ((size_t)hh * S + s) * HD;
    dst[d] = x0 * c0 - x1 * s0;
    dst[d + 32] = x1 * c1 + x0 * s1;
  } else {
    int hk = hh - NH;
    const float* src = k + (size_t)s * (NKV * HD) + hk * HD;
    float x0 = src[d], x1 = src[d + 32];
    float* dst = kr + ((size_t)hk * S + s) * HD;
    dst[d] = x0 * c0 - x1 * s0;
    dst[d + 32] = x1 * c1 + x0 * s1;
  }
}

__global__ __launch_bounds__(256) void vcopy_kernel(const float* __restrict__ v,
                                                    float* __restrict__ vr) {
  int i = blockIdx.x * 256 + threadIdx.x;
  int d = i & 63;
  int s = (i >> 6) & 2047;
  int hk = i >> 17;
  vr[((size_t)hk * S + s) * HD + d] = v[(size_t)s * (NKV * HD) + hk * HD + d];
}

// ---------------- flash attention (f32, lane-per-row) ----------------
__global__ __launch_bounds__(64) void flash_kernel(const float* __restrict__ qr,
                                                   const float* __restrict__ kr,
                                                   const float* __restrict__ vr,
                                                   const float* __restrict__ amask,
                                                   float* __restrict__ o_out) {
  int qt = blockIdx.x, head = blockIdx.y, lane = threadIdx.x;
  __shared__ __align__(16) float Qp[64 * 65];
  __shared__ __align__(16) float Kt[64 * 36];
  __shared__ __align__(16) float Vt[32 * 68];
  __shared__ float am[32];
  const float* qbase = qr + ((size_t)head * S + qt * 64) * HD;
  for (int r = 0; r < 64; r++) Qp[r * 65 + lane] = qbase[r * HD + lane];
  __syncthreads();
  int row = qt * 64 + lane;
  float o[64];
#pragma unroll
  for (int c = 0; c < 64; c++) o[c] = 0.f;
  float m = -1e30f, l = 0.f;
  const float* kbase = kr + (size_t)(head >> 1) * S * HD;
  const float* vbase = vr + (size_t)(head >> 1) * S * HD;
  int nkv = (qt + 1) * 2;
  for (int kb = 0; kb < nkv; kb++) {
    int kv0 = kb * 32;
    __syncthreads();
    {
      int j = lane >> 1, hf = (lane & 1) * 32;
      const float* ks = kbase + (size_t)(kv0 + j) * HD + hf;
#pragma unroll
      for (int i = 0; i < 32; i += 4) {
        float4 v4 = *(const float4*)(ks + i);
        Kt[(hf + i + 0) * 36 + j] = v4.x;
        Kt[(hf + i + 1) * 36 + j] = v4.y;
        Kt[(hf + i + 2) * 36 + j] = v4.z;
        Kt[(hf + i + 3) * 36 + j] = v4.w;
      }
      const float* vs = vbase + (size_t)(kv0 + j) * HD + hf;
#pragma unroll
      for (int i = 0; i < 32; i += 4) {
        *(float4*)&Vt[j * 68 + hf + i] = *(const float4*)(vs + i);
      }
      if (lane < 32) am[lane] = amask[kv0 + lane];
    }
    __syncthreads();
    float s[32];
#pragma unroll
    for (int jj = 0; jj < 32; jj++) s[jj] = 0.f;
    for (int d = 0; d < 64; d++) {
      float qd = Qp[lane * 65 + d];
#pragma unroll
      for (int jg = 0; jg < 8; jg++) {
        f32x4 k4 = *(f32x4*)&Kt[d * 36 + jg * 4];
        s[jg * 4 + 0] += qd * k4[0];
        s[jg * 4 + 1] += qd * k4[1];
        s[jg * 4 + 2] += qd * k4[2];
        s[jg * 4 + 3] += qd * k4[3];
      }
    }
    float mx = m;
#pragma unroll
    for (int jj = 0; jj < 32; jj++) {
      bool ok = (kv0 + jj <= row) && (am[jj] > 0.f);
      s[jj] = ok ? s[jj] * 0.125f : -1e30f;
      mx = fmaxf(mx, s[jj]);
    }
    float alpha = __expf(m - mx);
    m = mx;
    l *= alpha;
#pragma unroll
    for (int c = 0; c < 64; c++) o[c] *= alpha;
#pragma unroll
    for (int jj = 0; jj < 32; jj++) {
      s[jj] = __expf(s[jj] - mx);
      l += s[jj];
    }
#pragma unroll
    for (int jj = 0; jj < 32; jj++) {
      float pj = s[jj];
#pragma unroll
      for (int cg = 0; cg < 16; cg++) {
        f32x4 v4 = *(f32x4*)&Vt[jj * 68 + cg * 4];
        o[cg * 4 + 0] += pj * v4[0];
        o[cg * 4 + 1] += pj * v4[1];
        o[cg * 4 + 2] += pj * v4[2];
        o[cg * 4 + 3] += pj * v4[3];
      }
    }
  }
  float inv = 1.f / l;
  float* dst = o_out + (size_t)row * (NH * HD) + head * HD;
#pragma unroll
  for (int c = 0; c < 64; c += 4) {
    float4 v4 = {o[c] * inv, o[c + 1] * inv, o[c + 2] * inv, o[c + 3] * inv};
    *(float4*)(dst + c) = v4;
  }
}

// ---------------- router ----------------
__global__ __launch_bounds__(256) void router_kernel(const float* __restrict__ t,
                                                     const float* __restrict__ gw,
                                                     int* __restrict__ cnt,
                                                     int* __restrict__ idxb,
                                                     float* __restrict__ wgtb) {
  int tok = blockIdx.x * 4 + (threadIdx.x >> 6);
  int lane = threadIdx.x & 63;
  const float* tr = t + (size_t)tok * H;
  float acc[NE];
#pragma unroll
  for (int e = 0; e < NE; e++) acc[e] = 0.f;
#pragma unroll
  for (int i = 0; i < 16; i++) {
    float tv = tr[lane * 16 + i];
    const float* g = gw + (size_t)(lane * 16 + i) * NE;
#pragma unroll
    for (int e = 0; e < NE; e++) acc[e] += tv * g[e];
  }
#pragma unroll
  for (int off = 1; off < 64; off <<= 1) {
#pragma unroll
    for (int e = 0; e < NE; e++) acc[e] += __shfl_xor(acc[e], off);
  }
  if (lane == 0) {
    int e1 = 0;
#pragma unroll
    for (int e = 1; e < NE; e++)
      if (acc[e] > acc[e1]) e1 = e;
    int e2 = -1;
#pragma unroll
    for (int e = 0; e < NE; e++)
      if (e != e1 && (e2 < 0 || acc[e] > acc[e2])) e2 = e;
    float w1v = 1.f / (1.f + __expf(acc[e2] - acc[e1]));
    float w2v = 1.f - w1v;
    int p1 = atomicAdd(&cnt[e1], 1);
    idxb[e1 * S + p1] = tok;
    wgtb[e1 * S + p1] = w1v;
    int p2 = atomicAdd(&cnt[e2], 1);
    idxb[e2 * S + p2] = tok;
    wgtb[e2 * S + p2] = w2v;
  }
}

__global__ void offsets_kernel(const int* __restrict__ cnt, int* __restrict__ offs) {
  if (threadIdx.x == 0 && blockIdx.x == 0) {
    int a = 0;
    for (int e = 0; e < NE; e++) {
      offs[e] = a;
      a += cnt[e];
    }
    offs[NE] = a;
  }
}

__global__ __launch_bounds__(256) void final_add(const float* __restrict__ a,
                                                 const float* __restrict__ b,
                                                 float* __restrict__ o) {
  int i = blockIdx.x * 256 + threadIdx.x;
  o[i] = a[i] + b[i];
}

// ---------------- launch ----------------
extern "C" void kernel_launch(void* const* d_in, const int* in_sizes, int n_in,
                              void* d_out, int out_size, void* d_ws, size_t ws_size,
                              hipStream_t stream) {
  const float* x = (const float*)d_in[0];
  const float* amask = (const float*)d_in[1];
  const int* pos = (const int*)d_in[2];
  const float* sinb = (const float*)d_in[3];
  const float* cosb = (const float*)d_in[4];
  const float* wq = (const float*)d_in[5];
  const float* wk = (const float*)d_in[6];
  const float* wv = (const float*)d_in[7];
  const float* wo = (const float*)d_in[8];
  const float* ln1 = (const float*)d_in[9];
  const float* ln2 = (const float*)d_in[10];
  const float* gw = (const float*)d_in[11];
  const float* w1 = (const float*)d_in[12];
  const float* w3 = (const float*)d_in[13];
  const float* w2 = (const float*)d_in[14];
  float* out = (float*)d_out;

  char* ws = (char*)d_ws;
  const size_t MB = 1024 * 1024;
  float* h = (float*)(ws + 0 * MB);
  float* q = (float*)(ws + 8 * MB);
  float* k = (float*)(ws + 16 * MB);
  float* v = (float*)(ws + 20 * MB);
  float* q_r = (float*)(ws + 24 * MB);
  float* k_r = (float*)(ws + 32 * MB);
  float* v_r = (float*)(ws + 36 * MB);
  float* o_o = (float*)(ws + 40 * MB);
  float* x2 = (float*)(ws + 48 * MB);
  float* t = (float*)(ws + 56 * MB);
  float* macc = (float*)(ws + 64 * MB);
  unsigned short* G = (unsigned short*)(ws + 72 * MB);  // 4096 x 2048 bf16 = 16MB
  int* cnt = (int*)(ws + 89 * MB);
  int* offs = cnt + 16;
  int* idxb = cnt + 64;
  float* wgtb = (float*)(idxb + NE * S);

  hipMemsetAsync(cnt, 0, 16 * sizeof(int), stream);
  hipMemsetAsync(macc, 0, (size_t)S * H * sizeof(float), stream);

  rmsnorm_kernel<<<S, 256, 0, stream>>>(x, ln1, h);

  gemm_kernel<0><<<dim3(16, 32, 1), 256, 0, stream>>>(h, nullptr, wq, nullptr, q, nullptr,
                                                      nullptr, nullptr, nullptr, nullptr, nullptr,
                                                      1024, 1024);
  gemm_kernel<0><<<dim3(8, 32, 1), 256, 0, stream>>>(h, nullptr, wk, nullptr, k, nullptr, nullptr,
                                                     nullptr, nullptr, nullptr, nullptr, 512, 1024);
  gemm_kernel<0><<<dim3(8, 32, 1), 256, 0, stream>>>(h, nullptr, wv, nullptr, v, nullptr, nullptr,
                                                     nullptr, nullptr, nullptr, nullptr, 512, 1024);

  rope_kernel<<<6144, 256, 0, stream>>>(q, k, sinb, cosb, pos, q_r, k_r);
  vcopy_kernel<<<4096, 256, 0, stream>>>(v, v_r);

  flash_kernel<<<dim3(32, 16), 64, 0, stream>>>(q_r, k_r, v_r, amask, o_o);

  gemm_kernel<1><<<dim3(16, 32, 1), 256, 0, stream>>>(o_o, nullptr, wo, nullptr, x2, nullptr, x,
                                                      nullptr, nullptr, nullptr, nullptr, 1024,
                                                      1024);

  rmsnorm_kernel<<<S, 256, 0, stream>>>(x2, ln2, t);

  router_kernel<<<S / 4, 256, 0, stream>>>(t, gw, cnt, idxb, wgtb);
  offsets_kernel<<<1, 64, 0, stream>>>(cnt, offs);

  gemm_kernel<2><<<dim3(32, 32, 8), 256, 0, stream>>>(t, nullptr, w1, w3, nullptr, G, nullptr,
                                                      idxb, wgtb, cnt, offs, 2048, 1024);
  gemm_kernel<3><<<dim3(16, 32, 8), 256, 0, stream>>>(nullptr, G, w2, nullptr, macc, nullptr,
                                                      nullptr, idxb, wgtb, cnt, offs, 1024, 2048);

  final_add<<<8192, 256, 0, stream>>>(x2, macc, out);
}

// Round 2
// 971.433 us; speedup vs baseline: 2.0169x; 2.0169x over previous
//
#include <hip/hip_runtime.h>

#define S 2048
#define H 1024
#define NH 16
#define NKV 8
#define HD 64
#define NE 8
#define ID 2048

typedef short bf16x8 __attribute__((ext_vector_type(8)));
typedef float f32x4 __attribute__((ext_vector_type(4)));

__device__ __forceinline__ unsigned short f2bf(float f) {
  unsigned u = __builtin_bit_cast(unsigned, f);
  u += 0x7FFFu + ((u >> 16) & 1u);
  return (unsigned short)(u >> 16);
}
__device__ __forceinline__ float bf2f(unsigned short h) {
  unsigned u = ((unsigned)h) << 16;
  return __builtin_bit_cast(float, u);
}

// ---------------- RMSNorm ----------------
__global__ __launch_bounds__(256) void rmsnorm_kernel(const float* __restrict__ x,
                                                      const float* __restrict__ w,
                                                      float* __restrict__ out) {
  int row = blockIdx.x;
  const float* xr = x + (size_t)row * H;
  int tid = threadIdx.x;
  float v[4];
  float ss = 0.f;
#pragma unroll
  for (int i = 0; i < 4; i++) {
    v[i] = xr[tid + i * 256];
    ss += v[i] * v[i];
  }
#pragma unroll
  for (int off = 1; off < 64; off <<= 1) ss += __shfl_xor(ss, off);
  __shared__ float part[4];
  if ((tid & 63) == 0) part[tid >> 6] = ss;
  __syncthreads();
  float tot = part[0] + part[1] + part[2] + part[3];
  float r = rsqrtf(tot * (1.f / H) + 1e-6f);
  float* orow = out + (size_t)row * H;
#pragma unroll
  for (int i = 0; i < 4; i++) {
    int c = tid + i * 256;
    orow[c] = v[i] * r * w[c];
  }
}

// ---------------- generic MFMA GEMM ----------------
// MODE 0: QKV  (A f32 [M][K], B f32 [K][N], split-bf16 x3, C f32)
// MODE 1: OPROJ (same + residual add)
// MODE 2: MOEA (A = gathered t rows f32, dual B = w1/w3 bf16, epilogue silu(g1)*g3 -> G bf16)
// MODE 3: MOEB (A = G bf16, B = w2 bf16, epilogue scaled atomicAdd into moe_acc)
#define BM 64
#define BN 64
#define BK 32

template <int MODE>
__global__ __launch_bounds__(256) void gemm_kernel(
    const float* __restrict__ A, const unsigned short* __restrict__ Abf,
    const float* __restrict__ Bw, const float* __restrict__ Bw2,
    float* __restrict__ C, unsigned short* __restrict__ Gout,
    const float* __restrict__ resid, const int* __restrict__ idx,
    const float* __restrict__ wgt, const int* __restrict__ cnt,
    const int* __restrict__ offs, int N, int K) {
  int nt = blockIdx.x, rt = blockIdx.y, e = blockIdx.z;
  int m0 = rt * BM, n0 = nt * BN;
  int ce = 0, gbase = 0;
  if (MODE >= 2) {
    ce = cnt[e];
    if (m0 >= ce) return;
    gbase = offs[e];
  }
  const float* B1 = Bw + (MODE >= 2 ? (size_t)e * H * ID : 0);
  const float* B2 = (MODE == 2) ? (Bw2 + (size_t)e * H * ID) : nullptr;

  __shared__ __align__(16) unsigned short Ahi[BM * BK];
  __shared__ __align__(16) unsigned short Alo[BM * BK];
  __shared__ __align__(16) unsigned short Bhi[BN * BK];
  __shared__ __align__(16) unsigned short Blo[BN * BK];
  __shared__ __align__(16) unsigned short B2hi[BN * BK];

  int tid = threadIdx.x;
  int ar = tid >> 2, ac = (tid & 3) * 8;
  int bk = tid >> 3, bn = (tid & 7) * 8;

  int atok = 0;
  if (MODE == 2) {
    int rr = m0 + ar;
    atok = (rr < ce) ? idx[e * S + rr] : 0;
  }
  int agrow = 0;
  if (MODE == 3) {
    agrow = gbase + m0 + ar;
    if (agrow > 4095) agrow = 4095;
  }

  int w = tid >> 6, lane = tid & 63;
  int wm = w >> 1, wn = w & 1;
  int lr = lane & 15, lk = (lane >> 4) * 8;

  f32x4 acc[2][2], acc2[2][2];
#pragma unroll
  for (int i = 0; i < 2; i++)
#pragma unroll
    for (int j = 0; j < 2; j++) {
      acc[i][j] = f32x4{0.f, 0.f, 0.f, 0.f};
      acc2[i][j] = f32x4{0.f, 0.f, 0.f, 0.f};
    }

  for (int k0 = 0; k0 < K; k0 += BK) {
    __syncthreads();
    // stage A
    {
      bf16x8 hv, lv;
      if (MODE == 3) {
        hv = *(const bf16x8*)(Abf + (size_t)agrow * K + k0 + ac);
      } else {
        const float* src;
        if (MODE == 2)
          src = A + (size_t)atok * H + k0 + ac;
        else
          src = A + (size_t)(m0 + ar) * K + k0 + ac;
#pragma unroll
        for (int i = 0; i < 8; i++) {
          float vv = src[i];
          unsigned short h_ = f2bf(vv);
          hv[i] = (short)h_;
          if (MODE <= 1) lv[i] = (short)f2bf(vv - bf2f(h_));
        }
      }
      *(bf16x8*)&Ahi[ar * BK + ac] = hv;
      if (MODE <= 1) *(bf16x8*)&Alo[ar * BK + ac] = lv;
    }
    // stage B transposed: LDS [n][k]
    {
      const float* src = B1 + (size_t)(k0 + bk) * N + n0 + bn;
#pragma unroll
      for (int j = 0; j < 8; j++) {
        float vv = src[j];
        unsigned short h_ = f2bf(vv);
        Bhi[(bn + j) * BK + bk] = h_;
        if (MODE <= 1) Blo[(bn + j) * BK + bk] = f2bf(vv - bf2f(h_));
      }
      if (MODE == 2) {
        const float* src2 = B2 + (size_t)(k0 + bk) * N + n0 + bn;
#pragma unroll
        for (int j = 0; j < 8; j++) B2hi[(bn + j) * BK + bk] = f2bf(src2[j]);
      }
    }
    __syncthreads();
    // compute
    bf16x8 ah[2], al[2], bh[2], bl[2], b2f[2];
#pragma unroll
    for (int i = 0; i < 2; i++) {
      ah[i] = *(bf16x8*)&Ahi[(wm * 32 + i * 16 + lr) * BK + lk];
      bh[i] = *(bf16x8*)&Bhi[(wn * 32 + i * 16 + lr) * BK + lk];
      if (MODE <= 1) {
        al[i] = *(bf16x8*)&Alo[(wm * 32 + i * 16 + lr) * BK + lk];
        bl[i] = *(bf16x8*)&Blo[(wn * 32 + i * 16 + lr) * BK + lk];
      }
      if (MODE == 2) b2f[i] = *(bf16x8*)&B2hi[(wn * 32 + i * 16 + lr) * BK + lk];
    }
#pragma unroll
    for (int i = 0; i < 2; i++)
#pragma unroll
      for (int j = 0; j < 2; j++) {
        acc[i][j] = __builtin_amdgcn_mfma_f32_16x16x32_bf16(ah[i], bh[j], acc[i][j], 0, 0, 0);
        if (MODE <= 1) {
          // hi*lo cross terms give ~f32 accuracy; lo*lo term (~2^-18 rel) dropped
          acc[i][j] = __builtin_amdgcn_mfma_f32_16x16x32_bf16(ah[i], bl[j], acc[i][j], 0, 0, 0);
          acc[i][j] = __builtin_amdgcn_mfma_f32_16x16x32_bf16(al[i], bh[j], acc[i][j], 0, 0, 0);
        }
        if (MODE == 2)
          acc2[i][j] = __builtin_amdgcn_mfma_f32_16x16x32_bf16(ah[i], b2f[j], acc2[i][j], 0, 0, 0);
      }
  }
  // epilogue
#pragma unroll
  for (int i = 0; i < 2; i++)
#pragma unroll
    for (int j = 0; j < 2; j++)
#pragma unroll
      for (int r = 0; r < 4; r++) {
        int grow = wm * 32 + i * 16 + (lane >> 4) * 4 + r;
        int gcol = n0 + wn * 32 + j * 16 + lr;
        float v = acc[i][j][r];
        if (MODE == 0) {
          C[(size_t)(m0 + grow) * N + gcol] = v;
        } else if (MODE == 1) {
          C[(size_t)(m0 + grow) * N + gcol] = v + resid[(size_t)(m0 + grow) * N + gcol];
        } else if (MODE == 2) {
          if (m0 + grow < ce) {
            float g3 = acc2[i][j][r];
            float sg = v / (1.f + __expf(-v));
            Gout[(size_t)(gbase + m0 + grow) * ID + gcol] = f2bf(sg * g3);
          }
        } else {
          if (m0 + grow < ce) {
            int tok = idx[e * S + m0 + grow];
            float wv = wgt[e * S + m0 + grow];
            atomicAdd(&C[(size_t)tok * H + gcol], v * wv);
          }
        }
      }
}

// ---------------- RoPE ----------------
__global__ __launch_bounds__(256) void rope_kernel(
    const float* __restrict__ q, const float* __restrict__ k,
    const float* __restrict__ sinb, const float* __restrict__ cosb,
    const int* __restrict__ pos, float* __restrict__ qr, float* __restrict__ kr) {
  int i = blockIdx.x * 256 + threadIdx.x;
  int d = i & 31;
  int s = (i >> 5) & 2047;
  int hh = i >> 16;  // 32*2048 = 65536
  int p = pos[s];
  float c0 = cosb[p * HD + d], c1 = cosb[p * HD + d + 32];
  float s0 = sinb[p * HD + d], s1 = sinb[p * HD + d + 32];
  if (hh < NH) {
    const float* src = q + (size_t)s * (NH * HD) + hh * HD;
    float x0 = src[d], x1 = src[d + 32];
    float* dst = qr + ((size_t)hh * S + s) * HD;
    dst[d] = x0 * c0 - x1 * s0;
    dst[d + 32] = x1 * c1 + x0 * s1;
  } else {
    int hk = hh - NH;
    const float* src = k + (size_t)s * (NKV * HD) + hk * HD;
    float x0 = src[d], x1 = src[d + 32];
    float* dst = kr + ((size_t)hk * S + s) * HD;
    dst[d] = x0 * c0 - x1 * s0;
    dst[d + 32] = x1 * c1 + x0 * s1;
  }
}

__global__ __launch_bounds__(256) void vcopy_kernel(const float* __restrict__ v,
                                                    float* __restrict__ vr) {
  int i = blockIdx.x * 256 + threadIdx.x;
  int d = i & 63;
  int s = (i >> 6) & 2047;
  int hk = i >> 17;
  vr[((size_t)hk * S + s) * HD + d] = v[(size_t)s * (NKV * HD) + hk * HD + d];
}

// ---------------- flash attention v2 (f32, lane-per-row, kv-split partials) ----------------
// grid (32 qt, 16 heads, 4 kv-splits), 64 threads. Writes unnormalized partial
// (o, m, l) per split; combine_kernel merges.
__global__ __launch_bounds__(64, 2) void flash_kernel(const float* __restrict__ qr,
                                                      const float* __restrict__ kr,
                                                      const float* __restrict__ vr,
                                                      const float* __restrict__ amask,
                                                      float* __restrict__ po,
                                                      float* __restrict__ pm,
                                                      float* __restrict__ pl) {
  int qt = 31 - blockIdx.x;  // long blocks first for load balance
  int head = blockIdx.y, z = blockIdx.z;
  int lane = threadIdx.x;
  __shared__ __align__(16) float Kt[64 * 36];
  __shared__ __align__(16) float Vt[32 * 68];
  __shared__ float am[32];
  int row = qt * 64 + lane;

  // Q row in registers
  float q[64];
  const float* qbase = qr + ((size_t)head * S + row) * HD;
#pragma unroll
  for (int i = 0; i < 64; i += 4) {
    float4 v4 = *(const float4*)(qbase + i);
    q[i] = v4.x;
    q[i + 1] = v4.y;
    q[i + 2] = v4.z;
    q[i + 3] = v4.w;
  }

  float o[64];
#pragma unroll
  for (int c = 0; c < 64; c++) o[c] = 0.f;
  float m = -1e30f, l = 0.f;

  const float* kbase = kr + (size_t)(head >> 1) * S * HD;
  const float* vbase = vr + (size_t)(head >> 1) * S * HD;
  int nblk = (qt + 1) * 2;  // 32-row kv blocks in causal range
  int b0 = (z * nblk) >> 2, b1 = ((z + 1) * nblk) >> 2;

  for (int kb = b0; kb < b1; kb++) {
    int kv0 = kb * 32;
    __syncthreads();
    {
      int j = lane >> 1, hf = (lane & 1) * 32;
      const float* ks = kbase + (size_t)(kv0 + j) * HD + hf;
#pragma unroll
      for (int i = 0; i < 32; i += 4) {
        float4 v4 = *(const float4*)(ks + i);
        Kt[(hf + i + 0) * 36 + j] = v4.x;
        Kt[(hf + i + 1) * 36 + j] = v4.y;
        Kt[(hf + i + 2) * 36 + j] = v4.z;
        Kt[(hf + i + 3) * 36 + j] = v4.w;
      }
      const float* vs = vbase + (size_t)(kv0 + j) * HD + hf;
#pragma unroll
      for (int i = 0; i < 32; i += 4) {
        *(float4*)&Vt[j * 68 + hf + i] = *(const float4*)(vs + i);
      }
      if (lane < 32) am[lane] = amask[kv0 + lane];
    }
    __syncthreads();
    float s[32];
#pragma unroll
    for (int jj = 0; jj < 32; jj++) s[jj] = 0.f;
#pragma unroll
    for (int d = 0; d < 64; d++) {
      float qd = q[d];
#pragma unroll
      for (int jg = 0; jg < 8; jg++) {
        f32x4 k4 = *(f32x4*)&Kt[d * 36 + jg * 4];
        s[jg * 4 + 0] += qd * k4[0];
        s[jg * 4 + 1] += qd * k4[1];
        s[jg * 4 + 2] += qd * k4[2];
        s[jg * 4 + 3] += qd * k4[3];
      }
    }
    float mx = m;
#pragma unroll
    for (int jj = 0; jj < 32; jj++) {
      bool ok = (kv0 + jj <= row) && (am[jj] > 0.f);
      s[jj] = ok ? s[jj] * 0.125f : -1e30f;
      mx = fmaxf(mx, s[jj]);
    }
    float alpha = __expf(m - mx);
    m = mx;
    l *= alpha;
#pragma unroll
    for (int c = 0; c < 64; c++) o[c] *= alpha;
#pragma unroll
    for (int jj = 0; jj < 32; jj++) {
      s[jj] = __expf(s[jj] - mx);
      l += s[jj];
    }
#pragma unroll
    for (int jj = 0; jj < 32; jj++) {
      float pj = s[jj];
#pragma unroll
      for (int cg = 0; cg < 16; cg++) {
        f32x4 v4 = *(f32x4*)&Vt[jj * 68 + cg * 4];
        o[cg * 4 + 0] += pj * v4[0];
        o[cg * 4 + 1] += pj * v4[1];
        o[cg * 4 + 2] += pj * v4[2];
        o[cg * 4 + 3] += pj * v4[3];
      }
    }
  }
  // write partials (unnormalized)
  size_t pbase = (size_t)((qt * 16 + head) * 4 + z);
  pm[pbase * 64 + lane] = m;
  pl[pbase * 64 + lane] = l;
  float* pob = po + pbase * 4096 + (size_t)lane * 64;
#pragma unroll
  for (int c = 0; c < 64; c += 4) {
    float4 v4 = {o[c], o[c + 1], o[c + 2], o[c + 3]};
    *(float4*)(pob + c) = v4;
  }
}

// merge 4 kv-split partials -> o_out[s][h*64+d]
__global__ __launch_bounds__(256) void combine_kernel(const float* __restrict__ po,
                                                      const float* __restrict__ pm,
                                                      const float* __restrict__ pl,
                                                      float* __restrict__ o_out) {
  int qt = blockIdx.x, head = blockIdx.y;
  int r = threadIdx.x >> 2, dg = (threadIdx.x & 3) * 16;
  size_t base = (size_t)(qt * 16 + head) * 4;
  float mz[4], lz[4];
  float M = -1e30f;
#pragma unroll
  for (int z = 0; z < 4; z++) {
    mz[z] = pm[(base + z) * 64 + r];
    lz[z] = pl[(base + z) * 64 + r];
    M = fmaxf(M, mz[z]);
  }
  float L = 0.f, w[4];
#pragma unroll
  for (int z = 0; z < 4; z++) {
    w[z] = __expf(mz[z] - M);
    L += w[z] * lz[z];
  }
  float inv = 1.f / L;
  float acc[16];
#pragma unroll
  for (int i = 0; i < 16; i++) acc[i] = 0.f;
#pragma unroll
  for (int z = 0; z < 4; z++) {
    const float* p = po + (base + z) * 4096 + (size_t)r * 64 + dg;
    float wz = w[z];
#pragma unroll
    for (int i = 0; i < 16; i += 4) {
      float4 v4 = *(const float4*)(p + i);
      acc[i + 0] += wz * v4.x;
      acc[i + 1] += wz * v4.y;
      acc[i + 2] += wz * v4.z;
      acc[i + 3] += wz * v4.w;
    }
  }
  float* dst = o_out + (size_t)(qt * 64 + r) * (NH * HD) + head * HD + dg;
#pragma unroll
  for (int i = 0; i < 16; i += 4) {
    float4 v4 = {acc[i] * inv, acc[i + 1] * inv, acc[i + 2] * inv, acc[i + 3] * inv};
    *(float4*)(dst + i) = v4;
  }
}

// ---------------- router ----------------
__global__ __launch_bounds__(256) void router_kernel(const float* __restrict__ t,
                                                     const float* __restrict__ gw,
                                                     int* __restrict__ cnt,
                                                     int* __restrict__ idxb,
                                                     float* __restrict__ wgtb) {
  int tok = blockIdx.x * 4 + (threadIdx.x >> 6);
  int lane = threadIdx.x & 63;
  const float* tr = t + (size_t)tok * H;
  float acc[NE];
#pragma unroll
  for (int e = 0; e < NE; e++) acc[e] = 0.f;
#pragma unroll
  for (int i = 0; i < 16; i++) {
    float tv = tr[lane * 16 + i];
    const float* g = gw + (size_t)(lane * 16 + i) * NE;
#pragma unroll
    for (int e = 0; e < NE; e++) acc[e] += tv * g[e];
  }
#pragma unroll
  for (int off = 1; off < 64; off <<= 1) {
#pragma unroll
    for (int e = 0; e < NE; e++) acc[e] += __shfl_xor(acc[e], off);
  }
  if (lane == 0) {
    int e1 = 0;
#pragma unroll
    for (int e = 1; e < NE; e++)
      if (acc[e] > acc[e1]) e1 = e;
    int e2 = -1;
#pragma unroll
    for (int e = 0; e < NE; e++)
      if (e != e1 && (e2 < 0 || acc[e] > acc[e2])) e2 = e;
    float w1v = 1.f / (1.f + __expf(acc[e2] - acc[e1]));
    float w2v = 1.f - w1v;
    int p1 = atomicAdd(&cnt[e1], 1);
    idxb[e1 * S + p1] = tok;
    wgtb[e1 * S + p1] = w1v;
    int p2 = atomicAdd(&cnt[e2], 1);
    idxb[e2 * S + p2] = tok;
    wgtb[e2 * S + p2] = w2v;
  }
}

__global__ void offsets_kernel(const int* __restrict__ cnt, int* __restrict__ offs) {
  if (threadIdx.x == 0 && blockIdx.x == 0) {
    int a = 0;
    for (int e = 0; e < NE; e++) {
      offs[e] = a;
      a += cnt[e];
    }
    offs[NE] = a;
  }
}

__global__ __launch_bounds__(256) void final_add(const float* __restrict__ a,
                                                 const float* __restrict__ b,
                                                 float* __restrict__ o) {
  int i = blockIdx.x * 256 + threadIdx.x;
  o[i] = a[i] + b[i];
}

// ---------------- launch ----------------
extern "C" void kernel_launch(void* const* d_in, const int* in_sizes, int n_in,
                              void* d_out, int out_size, void* d_ws, size_t ws_size,
                              hipStream_t stream) {
  const float* x = (const float*)d_in[0];
  const float* amask = (const float*)d_in[1];
  const int* pos = (const int*)d_in[2];
  const float* sinb = (const float*)d_in[3];
  const float* cosb = (const float*)d_in[4];
  const float* wq = (const float*)d_in[5];
  const float* wk = (const float*)d_in[6];
  const float* wv = (const float*)d_in[7];
  const float* wo = (const float*)d_in[8];
  const float* ln1 = (const float*)d_in[9];
  const float* ln2 = (const float*)d_in[10];
  const float* gw = (const float*)d_in[11];
  const float* w1 = (const float*)d_in[12];
  const float* w3 = (const float*)d_in[13];
  const float* w2 = (const float*)d_in[14];
  float* out = (float*)d_out;

  char* ws = (char*)d_ws;
  const size_t MB = 1024 * 1024;
  float* q_r = (float*)(ws + 0 * MB);   // 8 MB   [live during flash]
  float* k_r = (float*)(ws + 8 * MB);   // 4 MB   [live during flash]
  float* v_r = (float*)(ws + 12 * MB);  // 4 MB   [live during flash]
  float* h = (float*)(ws + 16 * MB);    // 8 MB   [dead after QKV gemms]
  float* q = (float*)(ws + 24 * MB);    // 8 MB   [dead after rope]
  float* k = (float*)(ws + 32 * MB);    // 4 MB   [dead after rope]
  float* v = (float*)(ws + 36 * MB);    // 4 MB   [dead after vcopy]
  float* po = (float*)(ws + 16 * MB);   // 32 MB  [overlaps h/q/k/v: all dead by flash time]
  float* pm = (float*)(ws + 48 * MB);   // 0.5 MB
  float* pl = (float*)(ws + 49 * MB);   // 0.5 MB
  float* o_o = (float*)(ws + 50 * MB);  // 8 MB
  float* x2 = (float*)(ws + 58 * MB);   // 8 MB
  float* t = (float*)(ws + 66 * MB);    // 8 MB
  float* macc = (float*)(ws + 74 * MB); // 8 MB
  unsigned short* G = (unsigned short*)(ws + 82 * MB);  // 4096 x 2048 bf16 = 16 MB
  int* cnt = (int*)(ws + 98 * MB);
  int* offs = cnt + 16;
  int* idxb = cnt + 64;
  float* wgtb = (float*)(idxb + NE * S);

  hipMemsetAsync(cnt, 0, 16 * sizeof(int), stream);
  hipMemsetAsync(macc, 0, (size_t)S * H * sizeof(float), stream);

  rmsnorm_kernel<<<S, 256, 0, stream>>>(x, ln1, h);

  gemm_kernel<0><<<dim3(16, 32, 1), 256, 0, stream>>>(h, nullptr, wq, nullptr, q, nullptr,
                                                      nullptr, nullptr, nullptr, nullptr, nullptr,
                                                      1024, 1024);
  gemm_kernel<0><<<dim3(8, 32, 1), 256, 0, stream>>>(h, nullptr, wk, nullptr, k, nullptr, nullptr,
                                                     nullptr, nullptr, nullptr, nullptr, 512, 1024);
  gemm_kernel<0><<<dim3(8, 32, 1), 256, 0, stream>>>(h, nullptr, wv, nullptr, v, nullptr, nullptr,
                                                     nullptr, nullptr, nullptr, nullptr, 512, 1024);

  rope_kernel<<<6144, 256, 0, stream>>>(q, k, sinb, cosb, pos, q_r, k_r);
  vcopy_kernel<<<4096, 256, 0, stream>>>(v, v_r);

  flash_kernel<<<dim3(32, 16, 4), 64, 0, stream>>>(q_r, k_r, v_r, amask, po, pm, pl);
  combine_kernel<<<dim3(32, 16), 256, 0, stream>>>(po, pm, pl, o_o);

  gemm_kernel<1><<<dim3(16, 32, 1), 256, 0, stream>>>(o_o, nullptr, wo, nullptr, x2, nullptr, x,
                                                      nullptr, nullptr, nullptr, nullptr, 1024,
                                                      1024);

  rmsnorm_kernel<<<S, 256, 0, stream>>>(x2, ln2, t);

  router_kernel<<<S / 4, 256, 0, stream>>>(t, gw, cnt, idxb, wgtb);
  offsets_kernel<<<1, 64, 0, stream>>>(cnt, offs);

  gemm_kernel<2><<<dim3(32, 32, 8), 256, 0, stream>>>(t, nullptr, w1, w3, nullptr, G, nullptr,
                                                      idxb, wgtb, cnt, offs, 2048, 1024);
  gemm_kernel<3><<<dim3(16, 32, 8), 256, 0, stream>>>(nullptr, G, w2, nullptr, macc, nullptr,
                                                      nullptr, idxb, wgtb, cnt, offs, 1024, 2048);

  final_add<<<8192, 256, 0, stream>>>(x2, macc, out);
}

// Round 3
// 721.735 us; speedup vs baseline: 2.7147x; 1.3460x over previous
//
#include <hip/hip_runtime.h>

#define S 2048
#define H 1024
#define NH 16
#define NKV 8
#define HD 64
#define NE 8
#define ID 2048

typedef short bf16x8 __attribute__((ext_vector_type(8)));
typedef short bf16x4 __attribute__((ext_vector_type(4)));
typedef float f32x4 __attribute__((ext_vector_type(4)));

__device__ __forceinline__ unsigned short f2bf(float f) {
  unsigned u = __builtin_bit_cast(unsigned, f);
  u += 0x7FFFu + ((u >> 16) & 1u);
  return (unsigned short)(u >> 16);
}
__device__ __forceinline__ float bf2f(unsigned short h) {
  unsigned u = ((unsigned)h) << 16;
  return __builtin_bit_cast(float, u);
}

// ---------------- RMSNorm ----------------
__global__ __launch_bounds__(256) void rmsnorm_kernel(const float* __restrict__ x,
                                                      const float* __restrict__ w,
                                                      float* __restrict__ out) {
  int row = blockIdx.x;
  const float* xr = x + (size_t)row * H;
  int tid = threadIdx.x;
  float v[4];
  float ss = 0.f;
#pragma unroll
  for (int i = 0; i < 4; i++) {
    v[i] = xr[tid + i * 256];
    ss += v[i] * v[i];
  }
#pragma unroll
  for (int off = 1; off < 64; off <<= 1) ss += __shfl_xor(ss, off);
  __shared__ float part[4];
  if ((tid & 63) == 0) part[tid >> 6] = ss;
  __syncthreads();
  float tot = part[0] + part[1] + part[2] + part[3];
  float r = rsqrtf(tot * (1.f / H) + 1e-6f);
  float* orow = out + (size_t)row * H;
#pragma unroll
  for (int i = 0; i < 4; i++) {
    int c = tid + i * 256;
    orow[c] = v[i] * r * w[c];
  }
}

// ---------------- generic MFMA GEMM ----------------
// MODE 0: QKV  (A f32 [M][K], B f32 [K][N], split-bf16 x3, C f32)
// MODE 1: OPROJ (same + residual add)
// MODE 2: MOEA (A = gathered t rows f32, dual B = w1/w3 bf16, epilogue silu(g1)*g3 -> G bf16)
// MODE 3: MOEB (A = G bf16, B = w2 bf16, epilogue scaled atomicAdd into moe_acc)
#define BM 64
#define BN 64
#define BK 32

template <int MODE>
__global__ __launch_bounds__(256) void gemm_kernel(
    const float* __restrict__ A, const unsigned short* __restrict__ Abf,
    const float* __restrict__ Bw, const float* __restrict__ Bw2,
    float* __restrict__ C, unsigned short* __restrict__ Gout,
    const float* __restrict__ resid, const int* __restrict__ idx,
    const float* __restrict__ wgt, const int* __restrict__ cnt,
    const int* __restrict__ offs, int N, int K) {
  int nt = blockIdx.x, rt = blockIdx.y, e = blockIdx.z;
  int m0 = rt * BM, n0 = nt * BN;
  int ce = 0, gbase = 0;
  if (MODE >= 2) {
    ce = cnt[e];
    if (m0 >= ce) return;
    gbase = offs[e];
  }
  const float* B1 = Bw + (MODE >= 2 ? (size_t)e * H * ID : 0);
  const float* B2 = (MODE == 2) ? (Bw2 + (size_t)e * H * ID) : nullptr;

  __shared__ __align__(16) unsigned short Ahi[BM * BK];
  __shared__ __align__(16) unsigned short Alo[BM * BK];
  __shared__ __align__(16) unsigned short Bhi[BN * BK];
  __shared__ __align__(16) unsigned short Blo[BN * BK];
  __shared__ __align__(16) unsigned short B2hi[BN * BK];

  int tid = threadIdx.x;
  int ar = tid >> 2, ac = (tid & 3) * 8;
  int bk = tid >> 3, bn = (tid & 7) * 8;

  int atok = 0;
  if (MODE == 2) {
    int rr = m0 + ar;
    atok = (rr < ce) ? idx[e * S + rr] : 0;
  }
  int agrow = 0;
  if (MODE == 3) {
    agrow = gbase + m0 + ar;
    if (agrow > 4095) agrow = 4095;
  }

  int w = tid >> 6, lane = tid & 63;
  int wm = w >> 1, wn = w & 1;
  int lr = lane & 15, lk = (lane >> 4) * 8;

  f32x4 acc[2][2], acc2[2][2];
#pragma unroll
  for (int i = 0; i < 2; i++)
#pragma unroll
    for (int j = 0; j < 2; j++) {
      acc[i][j] = f32x4{0.f, 0.f, 0.f, 0.f};
      acc2[i][j] = f32x4{0.f, 0.f, 0.f, 0.f};
    }

  for (int k0 = 0; k0 < K; k0 += BK) {
    __syncthreads();
    // stage A
    {
      bf16x8 hv, lv;
      if (MODE == 3) {
        hv = *(const bf16x8*)(Abf + (size_t)agrow * K + k0 + ac);
      } else {
        const float* src;
        if (MODE == 2)
          src = A + (size_t)atok * H + k0 + ac;
        else
          src = A + (size_t)(m0 + ar) * K + k0 + ac;
#pragma unroll
        for (int i = 0; i < 8; i++) {
          float vv = src[i];
          unsigned short h_ = f2bf(vv);
          hv[i] = (short)h_;
          if (MODE <= 1) lv[i] = (short)f2bf(vv - bf2f(h_));
        }
      }
      *(bf16x8*)&Ahi[ar * BK + ac] = hv;
      if (MODE <= 1) *(bf16x8*)&Alo[ar * BK + ac] = lv;
    }
    // stage B transposed: LDS [n][k]
    {
      const float* src = B1 + (size_t)(k0 + bk) * N + n0 + bn;
#pragma unroll
      for (int j = 0; j < 8; j++) {
        float vv = src[j];
        unsigned short h_ = f2bf(vv);
        Bhi[(bn + j) * BK + bk] = h_;
        if (MODE <= 1) Blo[(bn + j) * BK + bk] = f2bf(vv - bf2f(h_));
      }
      if (MODE == 2) {
        const float* src2 = B2 + (size_t)(k0 + bk) * N + n0 + bn;
#pragma unroll
        for (int j = 0; j < 8; j++) B2hi[(bn + j) * BK + bk] = f2bf(src2[j]);
      }
    }
    __syncthreads();
    // compute
    bf16x8 ah[2], al[2], bh[2], bl[2], b2f[2];
#pragma unroll
    for (int i = 0; i < 2; i++) {
      ah[i] = *(bf16x8*)&Ahi[(wm * 32 + i * 16 + lr) * BK + lk];
      bh[i] = *(bf16x8*)&Bhi[(wn * 32 + i * 16 + lr) * BK + lk];
      if (MODE <= 1) {
        al[i] = *(bf16x8*)&Alo[(wm * 32 + i * 16 + lr) * BK + lk];
        bl[i] = *(bf16x8*)&Blo[(wn * 32 + i * 16 + lr) * BK + lk];
      }
      if (MODE == 2) b2f[i] = *(bf16x8*)&B2hi[(wn * 32 + i * 16 + lr) * BK + lk];
    }
#pragma unroll
    for (int i = 0; i < 2; i++)
#pragma unroll
      for (int j = 0; j < 2; j++) {
        acc[i][j] = __builtin_amdgcn_mfma_f32_16x16x32_bf16(ah[i], bh[j], acc[i][j], 0, 0, 0);
        if (MODE <= 1) {
          acc[i][j] = __builtin_amdgcn_mfma_f32_16x16x32_bf16(ah[i], bl[j], acc[i][j], 0, 0, 0);
          acc[i][j] = __builtin_amdgcn_mfma_f32_16x16x32_bf16(al[i], bh[j], acc[i][j], 0, 0, 0);
        }
        if (MODE == 2)
          acc2[i][j] = __builtin_amdgcn_mfma_f32_16x16x32_bf16(ah[i], b2f[j], acc2[i][j], 0, 0, 0);
      }
  }
  // epilogue
#pragma unroll
  for (int i = 0; i < 2; i++)
#pragma unroll
    for (int j = 0; j < 2; j++)
#pragma unroll
      for (int r = 0; r < 4; r++) {
        int grow = wm * 32 + i * 16 + (lane >> 4) * 4 + r;
        int gcol = n0 + wn * 32 + j * 16 + lr;
        float v = acc[i][j][r];
        if (MODE == 0) {
          C[(size_t)(m0 + grow) * N + gcol] = v;
        } else if (MODE == 1) {
          C[(size_t)(m0 + grow) * N + gcol] = v + resid[(size_t)(m0 + grow) * N + gcol];
        } else if (MODE == 2) {
          if (m0 + grow < ce) {
            float g3 = acc2[i][j][r];
            float sg = v / (1.f + __expf(-v));
            Gout[(size_t)(gbase + m0 + grow) * ID + gcol] = f2bf(sg * g3);
          }
        } else {
          if (m0 + grow < ce) {
            int tok = idx[e * S + m0 + grow];
            float wv = wgt[e * S + m0 + grow];
            atomicAdd(&C[(size_t)tok * H + gcol], v * wv);
          }
        }
      }
}

// ---------------- RoPE ----------------
__global__ __launch_bounds__(256) void rope_kernel(
    const float* __restrict__ q, const float* __restrict__ k,
    const float* __restrict__ sinb, const float* __restrict__ cosb,
    const int* __restrict__ pos, float* __restrict__ qr, float* __restrict__ kr) {
  int i = blockIdx.x * 256 + threadIdx.x;
  int d = i & 31;
  int s = (i >> 5) & 2047;
  int hh = i >> 16;  // 32*2048 = 65536
  int p = pos[s];
  float c0 = cosb[p * HD + d], c1 = cosb[p * HD + d + 32];
  float s0 = sinb[p * HD + d], s1 = sinb[p * HD + d + 32];
  if (hh < NH) {
    const float* src = q + (size_t)s * (NH * HD) + hh * HD;
    float x0 = src[d], x1 = src[d + 32];
    float* dst = qr + ((size_t)hh * S + s) * HD;
    dst[d] = x0 * c0 - x1 * s0;
    dst[d + 32] = x1 * c1 + x0 * s1;
  } else {
    int hk = hh - NH;
    const float* src = k + (size_t)s * (NKV * HD) + hk * HD;
    float x0 = src[d], x1 = src[d + 32];
    float* dst = kr + ((size_t)hk * S + s) * HD;
    dst[d] = x0 * c0 - x1 * s0;
    dst[d + 32] = x1 * c1 + x0 * s1;
  }
}

// ---------------- V transpose: v[s][hk*64+d] -> vT[hk][d][s] ----------------
__global__ __launch_bounds__(256) void vtrans_kernel(const float* __restrict__ v,
                                                     float* __restrict__ vT) {
  int st = blockIdx.x;  // 32 s-tiles of 64
  int hk = blockIdx.y;  // 8 kv heads
  __shared__ float tile[64][65];
  int tid = threadIdx.x;
  {
    int r = tid >> 2, seg = (tid & 3) * 16;
    const float* src = v + (size_t)(st * 64 + r) * (NKV * HD) + hk * HD + seg;
#pragma unroll
    for (int i = 0; i < 16; i += 4) {
      float4 a = *(const float4*)(src + i);
      tile[r][seg + i] = a.x;
      tile[r][seg + i + 1] = a.y;
      tile[r][seg + i + 2] = a.z;
      tile[r][seg + i + 3] = a.w;
    }
  }
  __syncthreads();
  {
    int d = tid >> 2, sseg = (tid & 3) * 16;
    float* dst = vT + ((size_t)hk * HD + d) * S + st * 64 + sseg;
#pragma unroll
    for (int i = 0; i < 16; i += 4) {
      float4 o = {tile[sseg + i][d], tile[sseg + i + 1][d], tile[sseg + i + 2][d],
                  tile[sseg + i + 3][d]};
      *(float4*)(dst + i) = o;
    }
  }
}

// ---------------- flash attention v3 (MFMA, split-bf16, swapped operands) ----------------
// 1 block = 4 waves, 64 q-rows (wave w owns rows w*16..w*16+15), KV-block = 64.
// QK^T via mfma(K, Q) -> lane holds q-row = lane&15. PV via mfma(V^T, P) -> same.
// XOR-swizzled LDS (byte ^= (row&7)<<4) for conflict-free ds_read_b128 frags.
#define FSWZ(row, byteoff) ((byteoff) ^ (((row) & 7) << 4))

__global__ __launch_bounds__(256) void flash_kernel(const float* __restrict__ qr,
                                                    const float* __restrict__ kr,
                                                    const float* __restrict__ vT,
                                                    const float* __restrict__ amask,
                                                    float* __restrict__ o_out) {
  int qt = (int)gridDim.x - 1 - (int)blockIdx.x;  // long blocks first
  int head = blockIdx.y;
  int tid = threadIdx.x;
  int w = tid >> 6, lane = tid & 63;
  int lr = lane & 15, g = lane >> 4;

  __shared__ __align__(16) unsigned short Khi[64 * 64];
  __shared__ __align__(16) unsigned short Klo[64 * 64];
  __shared__ __align__(16) unsigned short Vhi[64 * 64];
  __shared__ __align__(16) unsigned short Vlo[64 * 64];
  __shared__ __align__(16) unsigned short Phi[4][16 * 64];
  __shared__ __align__(16) unsigned short Plo[4][16 * 64];
  __shared__ unsigned long long vismask;

  // Q fragments in registers (B-operand layout: n=lr=q-row, k = kc*32 + g*8 + i).
  // Fold softmax scale 1/8 into Q (exact power of 2).
  int qrow = qt * 64 + w * 16 + lr;
  bf16x8 qh[2], ql[2];
  {
    const float* qb = qr + ((size_t)head * S + qrow) * HD;
#pragma unroll
    for (int kc = 0; kc < 2; kc++) {
      const float* p = qb + kc * 32 + g * 8;
      float4 a = *(const float4*)p;
      float4 b = *(const float4*)(p + 4);
      float tv[8] = {a.x, a.y, a.z, a.w, b.x, b.y, b.z, b.w};
#pragma unroll
      for (int i = 0; i < 8; i++) {
        float vv = tv[i] * 0.125f;
        unsigned short h_ = f2bf(vv);
        qh[kc][i] = (short)h_;
        ql[kc][i] = (short)f2bf(vv - bf2f(h_));
      }
    }
  }

  f32x4 oacc[4];
#pragma unroll
  for (int dg = 0; dg < 4; dg++) oacc[dg] = f32x4{0.f, 0.f, 0.f, 0.f};
  float m = -1e30f, l = 0.f;

  const float* kbase = kr + (size_t)(head >> 1) * S * HD;
  const float* vbase = vT + (size_t)(head >> 1) * HD * S;
  char* pbase = (char*)Phi[w];
  char* plbase = (char*)Plo[w];

  for (int kb = 0; kb <= qt; kb++) {
    int kv0 = kb * 64;
    __syncthreads();
    // ---- stage K[kv][d] and V^T[d][kv] as swizzled hi/lo bf16 ----
    {
      int row = tid >> 2, seg = (tid & 3) * 16;
      int b0 = row * 128 + seg * 2;
      {
        const float* ks = kbase + (size_t)(kv0 + row) * HD + seg;
        bf16x8 h0, h1, l0, l1;
#pragma unroll
        for (int i = 0; i < 8; i++) {
          float vv = ks[i];
          unsigned short h_ = f2bf(vv);
          h0[i] = (short)h_;
          l0[i] = (short)f2bf(vv - bf2f(h_));
        }
#pragma unroll
        for (int i = 0; i < 8; i++) {
          float vv = ks[8 + i];
          unsigned short h_ = f2bf(vv);
          h1[i] = (short)h_;
          l1[i] = (short)f2bf(vv - bf2f(h_));
        }
        *(bf16x8*)((char*)Khi + FSWZ(row, b0)) = h0;
        *(bf16x8*)((char*)Khi + FSWZ(row, b0 + 16)) = h1;
        *(bf16x8*)((char*)Klo + FSWZ(row, b0)) = l0;
        *(bf16x8*)((char*)Klo + FSWZ(row, b0 + 16)) = l1;
      }
      {
        const float* vs = vbase + (size_t)row * S + kv0 + seg;
        bf16x8 h0, h1, l0, l1;
#pragma unroll
        for (int i = 0; i < 8; i++) {
          float vv = vs[i];
          unsigned short h_ = f2bf(vv);
          h0[i] = (short)h_;
          l0[i] = (short)f2bf(vv - bf2f(h_));
        }
#pragma unroll
        for (int i = 0; i < 8; i++) {
          float vv = vs[8 + i];
          unsigned short h_ = f2bf(vv);
          h1[i] = (short)h_;
          l1[i] = (short)f2bf(vv - bf2f(h_));
        }
        *(bf16x8*)((char*)Vhi + FSWZ(row, b0)) = h0;
        *(bf16x8*)((char*)Vhi + FSWZ(row, b0 + 16)) = h1;
        *(bf16x8*)((char*)Vlo + FSWZ(row, b0)) = l0;
        *(bf16x8*)((char*)Vlo + FSWZ(row, b0 + 16)) = l1;
      }
      if (tid < 64) {
        unsigned long long bm = __ballot(amask[kv0 + tid] > 0.f);
        if (tid == 0) vismask = bm;
      }
    }
    __syncthreads();
    unsigned long long vm = vismask;

    // ---- QK^T (S^T): lane -> q-row lr, kv = c*16 + 4*g + r ----
    f32x4 sacc[4];
#pragma unroll
    for (int c = 0; c < 4; c++) sacc[c] = f32x4{0.f, 0.f, 0.f, 0.f};
#pragma unroll
    for (int c = 0; c < 4; c++) {
#pragma unroll
      for (int kc = 0; kc < 2; kc++) {
        int row = c * 16 + lr;
        int bo = FSWZ(row, row * 128 + kc * 64 + g * 16);
        bf16x8 khf = *(const bf16x8*)((char*)Khi + bo);
        bf16x8 klf = *(const bf16x8*)((char*)Klo + bo);
        sacc[c] = __builtin_amdgcn_mfma_f32_16x16x32_bf16(khf, qh[kc], sacc[c], 0, 0, 0);
        sacc[c] = __builtin_amdgcn_mfma_f32_16x16x32_bf16(khf, ql[kc], sacc[c], 0, 0, 0);
        sacc[c] = __builtin_amdgcn_mfma_f32_16x16x32_bf16(klf, qh[kc], sacc[c], 0, 0, 0);
      }
    }
    // ---- mask + online softmax (per-lane scalar m,l for q-row lr) ----
    int qloc = w * 16 + lr;
    bool diag = (kb == qt);
    float tm = -1e30f;
#pragma unroll
    for (int c = 0; c < 4; c++) {
#pragma unroll
      for (int r = 0; r < 4; r++) {
        int kvloc = c * 16 + 4 * g + r;
        bool vis = ((vm >> kvloc) & 1ull) && (!diag || kvloc <= qloc);
        float sv = vis ? sacc[c][r] : -1e30f;
        sacc[c][r] = sv;
        tm = fmaxf(tm, sv);
      }
    }
    tm = fmaxf(tm, __shfl_xor(tm, 16));
    tm = fmaxf(tm, __shfl_xor(tm, 32));
    float newm = fmaxf(m, tm);
    float alpha = __expf(m - newm);
    float rs = 0.f;
#pragma unroll
    for (int c = 0; c < 4; c++) {
#pragma unroll
      for (int r = 0; r < 4; r++) {
        float p = __expf(sacc[c][r] - newm);
        sacc[c][r] = p;
        rs += p;
      }
    }
    rs += __shfl_xor(rs, 16);
    rs += __shfl_xor(rs, 32);
    m = newm;
    l = l * alpha + rs;
#pragma unroll
    for (int dg = 0; dg < 4; dg++) {
#pragma unroll
      for (int r = 0; r < 4; r++) oacc[dg][r] *= alpha;
    }
    // ---- write P (hi/lo bf16) to per-wave LDS [q-row][kv], b64 packed ----
#pragma unroll
    for (int c = 0; c < 4; c++) {
      bf16x4 ph, pl2;
#pragma unroll
      for (int r = 0; r < 4; r++) {
        float pv = sacc[c][r];
        unsigned short h_ = f2bf(pv);
        ph[r] = (short)h_;
        pl2[r] = (short)f2bf(pv - bf2f(h_));
      }
      int bo = FSWZ(lr, lr * 128 + (c * 16 + 4 * g) * 2);
      *(bf16x4*)(pbase + bo) = ph;
      *(bf16x4*)(plbase + bo) = pl2;
    }
    // ---- PV (O^T += V^T * P^T): lane -> q-row lr, d = dg*16 + 4*g + r ----
    bf16x8 pbh[2], pbl[2];
#pragma unroll
    for (int kc = 0; kc < 2; kc++) {
      int bo = FSWZ(lr, lr * 128 + kc * 64 + g * 16);
      pbh[kc] = *(const bf16x8*)(pbase + bo);
      pbl[kc] = *(const bf16x8*)(plbase + bo);
    }
#pragma unroll
    for (int dg = 0; dg < 4; dg++) {
#pragma unroll
      for (int kc = 0; kc < 2; kc++) {
        int row = dg * 16 + lr;
        int bo = FSWZ(row, row * 128 + kc * 64 + g * 16);
        bf16x8 vhf = *(const bf16x8*)((char*)Vhi + bo);
        bf16x8 vlf = *(const bf16x8*)((char*)Vlo + bo);
        oacc[dg] = __builtin_amdgcn_mfma_f32_16x16x32_bf16(vhf, pbh[kc], oacc[dg], 0, 0, 0);
        oacc[dg] = __builtin_amdgcn_mfma_f32_16x16x32_bf16(vhf, pbl[kc], oacc[dg], 0, 0, 0);
        oacc[dg] = __builtin_amdgcn_mfma_f32_16x16x32_bf16(vlf, pbh[kc], oacc[dg], 0, 0, 0);
      }
    }
  }

  float inv = 1.f / l;
  float* dst = o_out + (size_t)qrow * (NH * HD) + head * HD;
#pragma unroll
  for (int dg = 0; dg < 4; dg++) {
    float4 v4 = {oacc[dg][0] * inv, oacc[dg][1] * inv, oacc[dg][2] * inv, oacc[dg][3] * inv};
    *(float4*)(dst + dg * 16 + 4 * g) = v4;
  }
}

// ---------------- router ----------------
__global__ __launch_bounds__(256) void router_kernel(const float* __restrict__ t,
                                                     const float* __restrict__ gw,
                                                     int* __restrict__ cnt,
                                                     int* __restrict__ idxb,
                                                     float* __restrict__ wgtb) {
  int tok = blockIdx.x * 4 + (threadIdx.x >> 6);
  int lane = threadIdx.x & 63;
  const float* tr = t + (size_t)tok * H;
  float acc[NE];
#pragma unroll
  for (int e = 0; e < NE; e++) acc[e] = 0.f;
#pragma unroll
  for (int i = 0; i < 16; i++) {
    float tv = tr[lane * 16 + i];
    const float* g = gw + (size_t)(lane * 16 + i) * NE;
#pragma unroll
    for (int e = 0; e < NE; e++) acc[e] += tv * g[e];
  }
#pragma unroll
  for (int off = 1; off < 64; off <<= 1) {
#pragma unroll
    for (int e = 0; e < NE; e++) acc[e] += __shfl_xor(acc[e], off);
  }
  if (lane == 0) {
    int e1 = 0;
#pragma unroll
    for (int e = 1; e < NE; e++)
      if (acc[e] > acc[e1]) e1 = e;
    int e2 = -1;
#pragma unroll
    for (int e = 0; e < NE; e++)
      if (e != e1 && (e2 < 0 || acc[e] > acc[e2])) e2 = e;
    float w1v = 1.f / (1.f + __expf(acc[e2] - acc[e1]));
    float w2v = 1.f - w1v;
    int p1 = atomicAdd(&cnt[e1], 1);
    idxb[e1 * S + p1] = tok;
    wgtb[e1 * S + p1] = w1v;
    int p2 = atomicAdd(&cnt[e2], 1);
    idxb[e2 * S + p2] = tok;
    wgtb[e2 * S + p2] = w2v;
  }
}

__global__ void offsets_kernel(const int* __restrict__ cnt, int* __restrict__ offs) {
  if (threadIdx.x == 0 && blockIdx.x == 0) {
    int a = 0;
    for (int e = 0; e < NE; e++) {
      offs[e] = a;
      a += cnt[e];
    }
    offs[NE] = a;
  }
}

__global__ __launch_bounds__(256) void final_add(const float* __restrict__ a,
                                                 const float* __restrict__ b,
                                                 float* __restrict__ o) {
  int i = blockIdx.x * 256 + threadIdx.x;
  o[i] = a[i] + b[i];
}

// ---------------- launch ----------------
extern "C" void kernel_launch(void* const* d_in, const int* in_sizes, int n_in,
                              void* d_out, int out_size, void* d_ws, size_t ws_size,
                              hipStream_t stream) {
  const float* x = (const float*)d_in[0];
  const float* amask = (const float*)d_in[1];
  const int* pos = (const int*)d_in[2];
  const float* sinb = (const float*)d_in[3];
  const float* cosb = (const float*)d_in[4];
  const float* wq = (const float*)d_in[5];
  const float* wk = (const float*)d_in[6];
  const float* wv = (const float*)d_in[7];
  const float* wo = (const float*)d_in[8];
  const float* ln1 = (const float*)d_in[9];
  const float* ln2 = (const float*)d_in[10];
  const float* gw = (const float*)d_in[11];
  const float* w1 = (const float*)d_in[12];
  const float* w3 = (const float*)d_in[13];
  const float* w2 = (const float*)d_in[14];
  float* out = (float*)d_out;

  char* ws = (char*)d_ws;
  const size_t MB = 1024 * 1024;
  float* q_r = (float*)(ws + 0 * MB);   // 8 MB
  float* k_r = (float*)(ws + 8 * MB);   // 4 MB
  float* vT = (float*)(ws + 12 * MB);   // 4 MB
  float* h = (float*)(ws + 16 * MB);    // 8 MB
  float* q = (float*)(ws + 24 * MB);    // 8 MB
  float* k = (float*)(ws + 32 * MB);    // 4 MB
  float* v = (float*)(ws + 36 * MB);    // 4 MB
  float* o_o = (float*)(ws + 40 * MB);  // 8 MB
  float* x2 = (float*)(ws + 48 * MB);   // 8 MB
  float* t = (float*)(ws + 56 * MB);    // 8 MB
  float* macc = (float*)(ws + 64 * MB); // 8 MB
  unsigned short* G = (unsigned short*)(ws + 72 * MB);  // 4096 x 2048 bf16 = 16 MB
  int* cnt = (int*)(ws + 89 * MB);
  int* offs = cnt + 16;
  int* idxb = cnt + 64;
  float* wgtb = (float*)(idxb + NE * S);

  hipMemsetAsync(cnt, 0, 16 * sizeof(int), stream);
  hipMemsetAsync(macc, 0, (size_t)S * H * sizeof(float), stream);

  rmsnorm_kernel<<<S, 256, 0, stream>>>(x, ln1, h);

  gemm_kernel<0><<<dim3(16, 32, 1), 256, 0, stream>>>(h, nullptr, wq, nullptr, q, nullptr,
                                                      nullptr, nullptr, nullptr, nullptr, nullptr,
                                                      1024, 1024);
  gemm_kernel<0><<<dim3(8, 32, 1), 256, 0, stream>>>(h, nullptr, wk, nullptr, k, nullptr, nullptr,
                                                     nullptr, nullptr, nullptr, nullptr, 512, 1024);
  gemm_kernel<0><<<dim3(8, 32, 1), 256, 0, stream>>>(h, nullptr, wv, nullptr, v, nullptr, nullptr,
                                                     nullptr, nullptr, nullptr, nullptr, 512, 1024);

  rope_kernel<<<6144, 256, 0, stream>>>(q, k, sinb, cosb, pos, q_r, k_r);
  vtrans_kernel<<<dim3(32, 8), 256, 0, stream>>>(v, vT);

  flash_kernel<<<dim3(32, 16), 256, 0, stream>>>(q_r, k_r, vT, amask, o_o);

  gemm_kernel<1><<<dim3(16, 32, 1), 256, 0, stream>>>(o_o, nullptr, wo, nullptr, x2, nullptr, x,
                                                      nullptr, nullptr, nullptr, nullptr, 1024,
                                                      1024);

  rmsnorm_kernel<<<S, 256, 0, stream>>>(x2, ln2, t);

  router_kernel<<<S / 4, 256, 0, stream>>>(t, gw, cnt, idxb, wgtb);
  offsets_kernel<<<1, 64, 0, stream>>>(cnt, offs);

  gemm_kernel<2><<<dim3(32, 32, 8), 256, 0, stream>>>(t, nullptr, w1, w3, nullptr, G, nullptr,
                                                      idxb, wgtb, cnt, offs, 2048, 1024);
  gemm_kernel<3><<<dim3(16, 32, 8), 256, 0, stream>>>(nullptr, G, w2, nullptr, macc, nullptr,
                                                      nullptr, idxb, wgtb, cnt, offs, 1024, 2048);

  final_add<<<8192, 256, 0, stream>>>(x2, macc, out);
}

// Round 4
// 480.363 us; speedup vs baseline: 4.0788x; 1.5025x over previous
//
#include <hip/hip_runtime.h>

#define S 2048
#define H 1024
#define NH 16
#define NKV 8
#define HD 64
#define NE 8
#define ID 2048

typedef short bf16x8 __attribute__((ext_vector_type(8)));
typedef short bf16x4 __attribute__((ext_vector_type(4)));
typedef float f32x4 __attribute__((ext_vector_type(4)));

__device__ __forceinline__ unsigned short f2bf(float f) {
  unsigned u = __builtin_bit_cast(unsigned, f);
  u += 0x7FFFu + ((u >> 16) & 1u);
  return (unsigned short)(u >> 16);
}
__device__ __forceinline__ float bf2f(unsigned short h) {
  unsigned u = ((unsigned)h) << 16;
  return __builtin_bit_cast(float, u);
}

typedef const __attribute__((address_space(1))) unsigned int gas_u32;
typedef __attribute__((address_space(3))) unsigned int las_u32;
// direct global->LDS DMA, 16B per lane; LDS dest = wave-uniform base + lane*16
__device__ __forceinline__ void gload16(const unsigned short* g, unsigned short* l) {
  __builtin_amdgcn_global_load_lds((gas_u32*)g, (las_u32*)l, 16, 0, 0);
}

// ---------------- RMSNorm ----------------
// OUTM 0: write hi+lo bf16 planes. OUTM 1: write f32 + hi bf16.
template <int OUTM>
__global__ __launch_bounds__(256) void rmsnorm_kernel(const float* __restrict__ x,
                                                      const float* __restrict__ wgt,
                                                      float* __restrict__ outf,
                                                      unsigned short* __restrict__ ohi,
                                                      unsigned short* __restrict__ olo) {
  int row = blockIdx.x;
  const float* xr = x + (size_t)row * H;
  int tid = threadIdx.x;
  float v[4];
  float ss = 0.f;
#pragma unroll
  for (int i = 0; i < 4; i++) {
    v[i] = xr[tid + i * 256];
    ss += v[i] * v[i];
  }
#pragma unroll
  for (int off = 1; off < 64; off <<= 1) ss += __shfl_xor(ss, off);
  __shared__ float part[4];
  if ((tid & 63) == 0) part[tid >> 6] = ss;
  __syncthreads();
  float tot = part[0] + part[1] + part[2] + part[3];
  float r = rsqrtf(tot * (1.f / H) + 1e-6f);
#pragma unroll
  for (int i = 0; i < 4; i++) {
    int c = tid + i * 256;
    float vv = v[i] * r * wgt[c];
    size_t o = (size_t)row * H + c;
    if (OUTM == 0) {
      unsigned short h_ = f2bf(vv);
      ohi[o] = h_;
      olo[o] = f2bf(vv - bf2f(h_));
    } else {
      outf[o] = vv;
      ohi[o] = f2bf(vv);
    }
  }
}

// ---------------- transpose-convert: src f32 [K][N] -> dst bf16 [N][K] ----------------
template <bool LO>
__global__ __launch_bounds__(256) void tconv_kernel(const float* __restrict__ src,
                                                    unsigned short* __restrict__ hi,
                                                    unsigned short* __restrict__ lo,
                                                    int K, int N, long long sStride,
                                                    long long dStride) {
  int nt = blockIdx.x, kt = blockIdx.y, b = blockIdx.z;
  src += (size_t)b * sStride;
  hi += (size_t)b * dStride;
  if (LO) lo += (size_t)b * dStride;
  __shared__ float tile[64][65];
  int tid = threadIdx.x;
  int r = tid >> 2, cs = (tid & 3) * 16;
  const float* s0 = src + (size_t)(kt * 64 + r) * N + nt * 64 + cs;
#pragma unroll
  for (int i = 0; i < 16; i += 4) {
    float4 a = *(const float4*)(s0 + i);
    tile[r][cs + i] = a.x;
    tile[r][cs + i + 1] = a.y;
    tile[r][cs + i + 2] = a.z;
    tile[r][cs + i + 3] = a.w;
  }
  __syncthreads();
  int n = nt * 64 + r;
  size_t dbase = (size_t)n * K + kt * 64 + cs;
  unsigned short th[16], tl[16];
#pragma unroll
  for (int i = 0; i < 16; i++) {
    float vv = tile[cs + i][r];
    unsigned short h_ = f2bf(vv);
    th[i] = h_;
    if (LO) tl[i] = f2bf(vv - bf2f(h_));
  }
  *(bf16x8*)(hi + dbase) = *(bf16x8*)&th[0];
  *(bf16x8*)(hi + dbase + 8) = *(bf16x8*)&th[8];
  if (LO) {
    *(bf16x8*)(lo + dbase) = *(bf16x8*)&tl[0];
    *(bf16x8*)(lo + dbase + 8) = *(bf16x8*)&tl[8];
  }
}

// ---------------- MFMA GEMM, 128x128 tile, BK=64, gload_lds + XOR swizzle ----------------
// MODE 0: QKV   A=h hi/lo [M][K], B=wqkvT hi/lo [N][K], 3-term split, C=qkv f32
// MODE 1: OPROJ same + resid, dual store (x2 and out)
// MODE 2: MOEA  A=t_bf gathered, Bh=w1T Bl=w3T (plain bf16), silu(g1)*g3 -> G bf16
// MODE 3: MOEB  A=G, B=w2T, atomicAdd out += v*wgt
template <int MODE>
__global__ __launch_bounds__(256) void gemm_kernel(
    const unsigned short* __restrict__ Ah, const unsigned short* __restrict__ Al,
    const unsigned short* __restrict__ Bh, const unsigned short* __restrict__ Bl,
    float* __restrict__ C, float* __restrict__ C2, unsigned short* __restrict__ Gout,
    const float* __restrict__ resid, const int* __restrict__ idx,
    const float* __restrict__ wgt, const int* __restrict__ cnt,
    const int* __restrict__ offs, int N, int K) {
  int n0 = blockIdx.x * 128, m0 = blockIdx.y * 128, e = blockIdx.z;
  int ce = 0, gbase = 0;
  if (MODE >= 2) {
    ce = cnt[e];
    if (m0 >= ce) return;
    gbase = offs[e];
  }
  const unsigned short* bhp = Bh;
  const unsigned short* blp = Bl;
  if (MODE == 2) {
    bhp += (size_t)e * 2048 * 1024;
    blp += (size_t)e * 2048 * 1024;
  }
  if (MODE == 3) bhp += (size_t)e * 1024 * 2048;

  __shared__ __align__(16) unsigned short tAh[128 * 64];
  __shared__ __align__(16) unsigned short tAl[128 * 64];
  __shared__ __align__(16) unsigned short tBh[128 * 64];
  __shared__ __align__(16) unsigned short tBl[128 * 64];

  int tid = threadIdx.x, w = tid >> 6, lane = tid & 63;
  int lr = lane & 15, g = lane >> 4;
  int rloc = lane >> 3, slotg = (lane & 7) ^ rloc;
  int wm = w >> 1, wn = w & 1;

  // per-chunk per-lane source element offsets (k0=0); inverse-swizzled slot
  unsigned aOff[4], bOff[4];
#pragma unroll
  for (int cc = 0; cc < 4; cc++) {
    int rr = w * 32 + cc * 8 + rloc;  // tile-local row 0..127
    bOff[cc] = (unsigned)((n0 + rr) * K + slotg * 8);
    if (MODE == 2) {
      int gr = m0 + rr;
      if (gr > ce - 1) gr = ce - 1;
      int tok = idx[e * S + gr];
      aOff[cc] = (unsigned)(tok * K + slotg * 8);
    } else if (MODE == 3) {
      int gr = gbase + m0 + rr;
      if (gr > 4095) gr = 4095;
      aOff[cc] = (unsigned)(gr * K + slotg * 8);
    } else {
      aOff[cc] = (unsigned)((m0 + rr) * K + slotg * 8);
    }
  }

  f32x4 acc[4][4], acc2[4][4];
#pragma unroll
  for (int i = 0; i < 4; i++)
#pragma unroll
    for (int j = 0; j < 4; j++) {
      acc[i][j] = f32x4{0.f, 0.f, 0.f, 0.f};
      if (MODE == 2) acc2[i][j] = f32x4{0.f, 0.f, 0.f, 0.f};
    }

  for (int k0 = 0; k0 < K; k0 += 64) {
    __syncthreads();
#pragma unroll
    for (int cc = 0; cc < 4; cc++) {
      int cb = (w * 4 + cc) * 512;
      gload16(Ah + aOff[cc] + k0, &tAh[cb]);
      gload16(bhp + bOff[cc] + k0, &tBh[cb]);
      if (MODE <= 1) {
        gload16(Al + aOff[cc] + k0, &tAl[cb]);
        gload16(blp + bOff[cc] + k0, &tBl[cb]);
      }
      if (MODE == 2) gload16(blp + bOff[cc] + k0, &tBl[cb]);
    }
    __syncthreads();
    bf16x8 fah[4][2], fal[4][2];
#pragma unroll
    for (int i = 0; i < 4; i++) {
      int ar = wm * 64 + i * 16 + lr;
#pragma unroll
      for (int kk = 0; kk < 2; kk++) {
        int off = ar * 64 + (((kk * 4 + g) ^ (ar & 7)) * 8);
        fah[i][kk] = *(const bf16x8*)&tAh[off];
        if (MODE <= 1) fal[i][kk] = *(const bf16x8*)&tAl[off];
      }
    }
#pragma unroll
    for (int j = 0; j < 4; j++) {
      int br = wn * 64 + j * 16 + lr;
      bf16x8 fbh[2], fbl[2];
#pragma unroll
      for (int kk = 0; kk < 2; kk++) {
        int off = br * 64 + (((kk * 4 + g) ^ (br & 7)) * 8);
        fbh[kk] = *(const bf16x8*)&tBh[off];
        if (MODE <= 2) fbl[kk] = *(const bf16x8*)&tBl[off];
      }
#pragma unroll
      for (int i = 0; i < 4; i++) {
#pragma unroll
        for (int kk = 0; kk < 2; kk++) {
          acc[i][j] = __builtin_amdgcn_mfma_f32_16x16x32_bf16(fah[i][kk], fbh[kk], acc[i][j], 0, 0, 0);
          if (MODE <= 1) {
            acc[i][j] = __builtin_amdgcn_mfma_f32_16x16x32_bf16(fah[i][kk], fbl[kk], acc[i][j], 0, 0, 0);
            acc[i][j] = __builtin_amdgcn_mfma_f32_16x16x32_bf16(fal[i][kk], fbh[kk], acc[i][j], 0, 0, 0);
          }
          if (MODE == 2)
            acc2[i][j] = __builtin_amdgcn_mfma_f32_16x16x32_bf16(fah[i][kk], fbl[kk], acc2[i][j], 0, 0, 0);
        }
      }
    }
  }
  // epilogue
#pragma unroll
  for (int i = 0; i < 4; i++)
#pragma unroll
    for (int j = 0; j < 4; j++)
#pragma unroll
      for (int r = 0; r < 4; r++) {
        int grow = wm * 64 + i * 16 + g * 4 + r;
        int gcol = n0 + wn * 64 + j * 16 + lr;
        float v = acc[i][j][r];
        if (MODE == 0) {
          C[(size_t)(m0 + grow) * N + gcol] = v;
        } else if (MODE == 1) {
          float o = v + resid[(size_t)(m0 + grow) * N + gcol];
          C[(size_t)(m0 + grow) * N + gcol] = o;
          C2[(size_t)(m0 + grow) * N + gcol] = o;
        } else if (MODE == 2) {
          if (m0 + grow < ce) {
            float g3 = acc2[i][j][r];
            float sg = v / (1.f + __expf(-v));
            Gout[(size_t)(gbase + m0 + grow) * 2048 + gcol] = f2bf(sg * g3);
          }
        } else {
          if (m0 + grow < ce) {
            int tok = idx[e * S + m0 + grow];
            float wv = wgt[e * S + m0 + grow];
            atomicAdd(&C[(size_t)tok * 1024 + gcol], v * wv);
          }
        }
      }
}

// ---------------- RoPE: qkv f32 -> q hi/lo (x0.125), k hi/lo planes ----------------
__global__ __launch_bounds__(256) void rope_kernel(
    const float* __restrict__ qkv, const float* __restrict__ sinb,
    const float* __restrict__ cosb, const int* __restrict__ pos,
    unsigned short* __restrict__ qhi, unsigned short* __restrict__ qlo,
    unsigned short* __restrict__ khi, unsigned short* __restrict__ klo) {
  int i = blockIdx.x * 256 + threadIdx.x;
  int d = i & 31;
  int s = (i >> 5) & 2047;
  int hh = i >> 16;  // 0..23
  int p = pos[s];
  float c0 = cosb[p * HD + d], c1 = cosb[p * HD + d + 32];
  float s0 = sinb[p * HD + d], s1 = sinb[p * HD + d + 32];
  const float* srcb = qkv + (size_t)s * 2048;
  if (hh < NH) {
    float x0 = srcb[hh * HD + d], x1 = srcb[hh * HD + d + 32];
    float r0 = (x0 * c0 - x1 * s0) * 0.125f;
    float r1 = (x1 * c1 + x0 * s1) * 0.125f;
    size_t o = ((size_t)hh * S + s) * HD + d;
    unsigned short h0 = f2bf(r0), h1 = f2bf(r1);
    qhi[o] = h0;
    qlo[o] = f2bf(r0 - bf2f(h0));
    qhi[o + 32] = h1;
    qlo[o + 32] = f2bf(r1 - bf2f(h1));
  } else {
    int hk = hh - NH;
    float x0 = srcb[1024 + hk * HD + d], x1 = srcb[1024 + hk * HD + d + 32];
    float r0 = x0 * c0 - x1 * s0;
    float r1 = x1 * c1 + x0 * s1;
    size_t o = ((size_t)hk * S + s) * HD + d;
    unsigned short h0 = f2bf(r0), h1 = f2bf(r1);
    khi[o] = h0;
    klo[o] = f2bf(r0 - bf2f(h0));
    khi[o + 32] = h1;
    klo[o + 32] = f2bf(r1 - bf2f(h1));
  }
}

// ---------------- V transpose: qkv v-cols -> vT[hk][d][s] hi/lo bf16 ----------------
__global__ __launch_bounds__(256) void vtrans_kernel(const float* __restrict__ qkv,
                                                     unsigned short* __restrict__ vThi,
                                                     unsigned short* __restrict__ vTlo) {
  int st = blockIdx.x, hk = blockIdx.y;
  __shared__ float tile[64][65];
  int tid = threadIdx.x;
  int r = tid >> 2, seg = (tid & 3) * 16;
  const float* src = qkv + (size_t)(st * 64 + r) * 2048 + 1536 + hk * HD + seg;
#pragma unroll
  for (int i = 0; i < 16; i += 4) {
    float4 a = *(const float4*)(src + i);
    tile[r][seg + i] = a.x;
    tile[r][seg + i + 1] = a.y;
    tile[r][seg + i + 2] = a.z;
    tile[r][seg + i + 3] = a.w;
  }
  __syncthreads();
  int d = tid >> 2, ss = (tid & 3) * 16;
  unsigned short th[16], tl[16];
#pragma unroll
  for (int i = 0; i < 16; i++) {
    float vv = tile[ss + i][d];
    unsigned short h_ = f2bf(vv);
    th[i] = h_;
    tl[i] = f2bf(vv - bf2f(h_));
  }
  size_t dst = ((size_t)hk * HD + d) * S + st * 64 + ss;
  *(bf16x8*)(vThi + dst) = *(bf16x8*)&th[0];
  *(bf16x8*)(vThi + dst + 8) = *(bf16x8*)&th[8];
  *(bf16x8*)(vTlo + dst) = *(bf16x8*)&tl[0];
  *(bf16x8*)(vTlo + dst + 8) = *(bf16x8*)&tl[8];
}

// ---------------- flash attention (MFMA, pre-split bf16, gload_lds staging) ----------------
#define FSWZ(row, byteoff) ((byteoff) ^ (((row) & 7) << 4))

__global__ __launch_bounds__(256) void flash_kernel(
    const unsigned short* __restrict__ qhi, const unsigned short* __restrict__ qlo,
    const unsigned short* __restrict__ khip, const unsigned short* __restrict__ klop,
    const unsigned short* __restrict__ vthip, const unsigned short* __restrict__ vtlop,
    const float* __restrict__ amask, unsigned short* __restrict__ ohi,
    unsigned short* __restrict__ olo) {
  int qt = (int)gridDim.x - 1 - (int)blockIdx.x;  // long blocks first
  int head = blockIdx.y;
  int tid = threadIdx.x;
  int w = tid >> 6, lane = tid & 63;
  int lr = lane & 15, g = lane >> 4;
  int rloc = lane >> 3, slotg = (lane & 7) ^ rloc;

  __shared__ __align__(16) unsigned short Khi[64 * 64];
  __shared__ __align__(16) unsigned short Klo[64 * 64];
  __shared__ __align__(16) unsigned short Vhi[64 * 64];
  __shared__ __align__(16) unsigned short Vlo[64 * 64];
  __shared__ __align__(16) unsigned short Phi[4][16 * 64];
  __shared__ __align__(16) unsigned short Plo[4][16 * 64];
  __shared__ unsigned long long vismask;

  int qrow = qt * 64 + w * 16 + lr;
  bf16x8 qh[2], ql[2];
  {
    const unsigned short* qb = qhi + ((size_t)head * S + qrow) * HD;
    const unsigned short* qb2 = qlo + ((size_t)head * S + qrow) * HD;
    qh[0] = *(const bf16x8*)(qb + g * 8);
    qh[1] = *(const bf16x8*)(qb + 32 + g * 8);
    ql[0] = *(const bf16x8*)(qb2 + g * 8);
    ql[1] = *(const bf16x8*)(qb2 + 32 + g * 8);
  }

  f32x4 oacc[4];
#pragma unroll
  for (int dg = 0; dg < 4; dg++) oacc[dg] = f32x4{0.f, 0.f, 0.f, 0.f};
  float m = -1e30f, l = 0.f;

  const unsigned short* kbh = khip + (size_t)(head >> 1) * S * HD;
  const unsigned short* kbl = klop + (size_t)(head >> 1) * S * HD;
  const unsigned short* vbh = vthip + (size_t)(head >> 1) * HD * S;
  const unsigned short* vbl = vtlop + (size_t)(head >> 1) * HD * S;
  char* pbase = (char*)Phi[w];
  char* plbase = (char*)Plo[w];

  for (int kb = 0; kb <= qt; kb++) {
    int kv0 = kb * 64;
    __syncthreads();
#pragma unroll
    for (int cc = 0; cc < 2; cc++) {
      int c = w * 2 + cc;
      int r = c * 8 + rloc;
      gload16(kbh + (size_t)(kv0 + r) * HD + slotg * 8, &Khi[c * 512]);
      gload16(kbl + (size_t)(kv0 + r) * HD + slotg * 8, &Klo[c * 512]);
      gload16(vbh + (size_t)r * S + kv0 + slotg * 8, &Vhi[c * 512]);
      gload16(vbl + (size_t)r * S + kv0 + slotg * 8, &Vlo[c * 512]);
    }
    if (tid < 64) {
      unsigned long long bm = __ballot(amask[kv0 + tid] > 0.f);
      if (tid == 0) vismask = bm;
    }
    __syncthreads();
    unsigned long long vm = vismask;

    // ---- QK^T (S^T): lane -> q-row lr, kv = c*16 + 4*g + r ----
    f32x4 sacc[4];
#pragma unroll
    for (int c = 0; c < 4; c++) sacc[c] = f32x4{0.f, 0.f, 0.f, 0.f};
#pragma unroll
    for (int c = 0; c < 4; c++) {
#pragma unroll
      for (int kc = 0; kc < 2; kc++) {
        int row = c * 16 + lr;
        int bo = FSWZ(row, row * 128 + kc * 64 + g * 16);
        bf16x8 khf = *(const bf16x8*)((char*)Khi + bo);
        bf16x8 klf = *(const bf16x8*)((char*)Klo + bo);
        sacc[c] = __builtin_amdgcn_mfma_f32_16x16x32_bf16(khf, qh[kc], sacc[c], 0, 0, 0);
        sacc[c] = __builtin_amdgcn_mfma_f32_16x16x32_bf16(khf, ql[kc], sacc[c], 0, 0, 0);
        sacc[c] = __builtin_amdgcn_mfma_f32_16x16x32_bf16(klf, qh[kc], sacc[c], 0, 0, 0);
      }
    }
    // ---- mask + online softmax ----
    int qloc = w * 16 + lr;
    bool diag = (kb == qt);
    float tm = -1e30f;
#pragma unroll
    for (int c = 0; c < 4; c++) {
#pragma unroll
      for (int r = 0; r < 4; r++) {
        int kvloc = c * 16 + 4 * g + r;
        bool vis = ((vm >> kvloc) & 1ull) && (!diag || kvloc <= qloc);
        float sv = vis ? sacc[c][r] : -1e30f;
        sacc[c][r] = sv;
        tm = fmaxf(tm, sv);
      }
    }
    tm = fmaxf(tm, __shfl_xor(tm, 16));
    tm = fmaxf(tm, __shfl_xor(tm, 32));
    float newm = fmaxf(m, tm);
    float alpha = __expf(m - newm);
    float rs = 0.f;
#pragma unroll
    for (int c = 0; c < 4; c++) {
#pragma unroll
      for (int r = 0; r < 4; r++) {
        float p = __expf(sacc[c][r] - newm);
        sacc[c][r] = p;
        rs += p;
      }
    }
    rs += __shfl_xor(rs, 16);
    rs += __shfl_xor(rs, 32);
    m = newm;
    l = l * alpha + rs;
#pragma unroll
    for (int dg = 0; dg < 4; dg++) {
#pragma unroll
      for (int r = 0; r < 4; r++) oacc[dg][r] *= alpha;
    }
    // ---- write P hi/lo to per-wave LDS ----
#pragma unroll
    for (int c = 0; c < 4; c++) {
      bf16x4 ph, pl2;
#pragma unroll
      for (int r = 0; r < 4; r++) {
        float pv = sacc[c][r];
        unsigned short h_ = f2bf(pv);
        ph[r] = (short)h_;
        pl2[r] = (short)f2bf(pv - bf2f(h_));
      }
      int bo = FSWZ(lr, lr * 128 + (c * 16 + 4 * g) * 2);
      *(bf16x4*)(pbase + bo) = ph;
      *(bf16x4*)(plbase + bo) = pl2;
    }
    // ---- PV: O^T += V^T * P^T ----
    bf16x8 pbh[2], pbl[2];
#pragma unroll
    for (int kc = 0; kc < 2; kc++) {
      int bo = FSWZ(lr, lr * 128 + kc * 64 + g * 16);
      pbh[kc] = *(const bf16x8*)(pbase + bo);
      pbl[kc] = *(const bf16x8*)(plbase + bo);
    }
#pragma unroll
    for (int dg = 0; dg < 4; dg++) {
#pragma unroll
      for (int kc = 0; kc < 2; kc++) {
        int row = dg * 16 + lr;
        int bo = FSWZ(row, row * 128 + kc * 64 + g * 16);
        bf16x8 vhf = *(const bf16x8*)((char*)Vhi + bo);
        bf16x8 vlf = *(const bf16x8*)((char*)Vlo + bo);
        oacc[dg] = __builtin_amdgcn_mfma_f32_16x16x32_bf16(vhf, pbh[kc], oacc[dg], 0, 0, 0);
        oacc[dg] = __builtin_amdgcn_mfma_f32_16x16x32_bf16(vhf, pbl[kc], oacc[dg], 0, 0, 0);
        oacc[dg] = __builtin_amdgcn_mfma_f32_16x16x32_bf16(vlf, pbh[kc], oacc[dg], 0, 0, 0);
      }
    }
  }

  float inv = 1.f / l;
  size_t ob = (size_t)qrow * 1024 + head * HD;
#pragma unroll
  for (int dg = 0; dg < 4; dg++) {
    bf16x4 th, tl;
#pragma unroll
    for (int r = 0; r < 4; r++) {
      float vv = oacc[dg][r] * inv;
      unsigned short h_ = f2bf(vv);
      th[r] = (short)h_;
      tl[r] = (short)f2bf(vv - bf2f(h_));
    }
    *(bf16x4*)(ohi + ob + dg * 16 + 4 * g) = th;
    *(bf16x4*)(olo + ob + dg * 16 + 4 * g) = tl;
  }
}

// ---------------- router ----------------
__global__ __launch_bounds__(256) void router_kernel(const float* __restrict__ t,
                                                     const float* __restrict__ gw,
                                                     int* __restrict__ cnt,
                                                     int* __restrict__ idxb,
                                                     float* __restrict__ wgtb) {
  int tok = blockIdx.x * 4 + (threadIdx.x >> 6);
  int lane = threadIdx.x & 63;
  const float* tr = t + (size_t)tok * H;
  float acc[NE];
#pragma unroll
  for (int e = 0; e < NE; e++) acc[e] = 0.f;
#pragma unroll
  for (int i = 0; i < 16; i++) {
    float tv = tr[lane * 16 + i];
    const float* g = gw + (size_t)(lane * 16 + i) * NE;
#pragma unroll
    for (int e = 0; e < NE; e++) acc[e] += tv * g[e];
  }
#pragma unroll
  for (int off = 1; off < 64; off <<= 1) {
#pragma unroll
    for (int e = 0; e < NE; e++) acc[e] += __shfl_xor(acc[e], off);
  }
  if (lane == 0) {
    int e1 = 0;
#pragma unroll
    for (int e = 1; e < NE; e++)
      if (acc[e] > acc[e1]) e1 = e;
    int e2 = -1;
#pragma unroll
    for (int e = 0; e < NE; e++)
      if (e != e1 && (e2 < 0 || acc[e] > acc[e2])) e2 = e;
    float w1v = 1.f / (1.f + __expf(acc[e2] - acc[e1]));
    float w2v = 1.f - w1v;
    int p1 = atomicAdd(&cnt[e1], 1);
    idxb[e1 * S + p1] = tok;
    wgtb[e1 * S + p1] = w1v;
    int p2 = atomicAdd(&cnt[e2], 1);
    idxb[e2 * S + p2] = tok;
    wgtb[e2 * S + p2] = w2v;
  }
}

__global__ void offsets_kernel(const int* __restrict__ cnt, int* __restrict__ offs) {
  if (threadIdx.x == 0 && blockIdx.x == 0) {
    int a = 0;
    for (int e = 0; e < NE; e++) {
      offs[e] = a;
      a += cnt[e];
    }
    offs[NE] = a;
  }
}

// ---------------- launch ----------------
extern "C" void kernel_launch(void* const* d_in, const int* in_sizes, int n_in,
                              void* d_out, int out_size, void* d_ws, size_t ws_size,
                              hipStream_t stream) {
  const float* x = (const float*)d_in[0];
  const float* amask = (const float*)d_in[1];
  const int* pos = (const int*)d_in[2];
  const float* sinb = (const float*)d_in[3];
  const float* cosb = (const float*)d_in[4];
  const float* wq = (const float*)d_in[5];
  const float* wk = (const float*)d_in[6];
  const float* wv = (const float*)d_in[7];
  const float* wo = (const float*)d_in[8];
  const float* ln1 = (const float*)d_in[9];
  const float* ln2 = (const float*)d_in[10];
  const float* gw = (const float*)d_in[11];
  const float* w1 = (const float*)d_in[12];
  const float* w3 = (const float*)d_in[13];
  const float* w2 = (const float*)d_in[14];
  float* out = (float*)d_out;

  char* ws = (char*)d_ws;
  const size_t MB = 1024 * 1024;
  // persistent
  float* x2 = (float*)(ws + 0 * MB);                    // 8 MB
  unsigned short* t_bf = (unsigned short*)(ws + 8 * MB);  // 4 MB
  int* cnt = (int*)(ws + 12 * MB);
  int* offs = cnt + 16;
  int* idxb = cnt + 64;
  float* wgtb = (float*)(idxb + NE * S);
  // MoE region
  unsigned short* G = (unsigned short*)(ws + 13 * MB);    // 16 MB: 13-29
  unsigned short* w1T = (unsigned short*)(ws + 29 * MB);  // 32 MB: 29-61
  unsigned short* w3T = (unsigned short*)(ws + 61 * MB);  // 32 MB: 61-93
  unsigned short* w2T = (unsigned short*)(ws + 29 * MB);  // reuse after mode2
  // phase-1 overlays (dead before MoE tconvs run)
  float* qkv = (float*)(ws + 13 * MB);                       // 16 MB: 13-29
  unsigned short* wqkvT_hi = (unsigned short*)(ws + 29 * MB);  // 4 MB
  unsigned short* wqkvT_lo = (unsigned short*)(ws + 33 * MB);  // 4 MB
  unsigned short* woT_hi = (unsigned short*)(ws + 37 * MB);    // 2 MB
  unsigned short* woT_lo = (unsigned short*)(ws + 39 * MB);    // 2 MB
  unsigned short* h_hi = (unsigned short*)(ws + 41 * MB);      // 4 MB
  unsigned short* h_lo = (unsigned short*)(ws + 45 * MB);      // 4 MB
  unsigned short* q_hi = (unsigned short*)(ws + 49 * MB);      // 4 MB
  unsigned short* q_lo = (unsigned short*)(ws + 53 * MB);      // 4 MB
  unsigned short* k_hi = (unsigned short*)(ws + 57 * MB);      // 2 MB
  unsigned short* k_lo = (unsigned short*)(ws + 59 * MB);      // 2 MB
  unsigned short* vT_hi = (unsigned short*)(ws + 61 * MB);     // 2 MB
  unsigned short* vT_lo = (unsigned short*)(ws + 63 * MB);     // 2 MB
  unsigned short* o_hi = (unsigned short*)(ws + 65 * MB);      // 4 MB
  unsigned short* o_lo = (unsigned short*)(ws + 69 * MB);      // 4 MB
  float* t = (float*)(ws + 73 * MB);                           // 8 MB: 73-81

  hipMemsetAsync(cnt, 0, 16 * sizeof(int), stream);

  // attention block
  rmsnorm_kernel<0><<<S, 256, 0, stream>>>(x, ln1, nullptr, h_hi, h_lo);
  tconv_kernel<true><<<dim3(16, 16, 1), 256, 0, stream>>>(wq, wqkvT_hi, wqkvT_lo, 1024, 1024, 0, 0);
  tconv_kernel<true><<<dim3(8, 16, 1), 256, 0, stream>>>(wk, wqkvT_hi + (size_t)1024 * 1024,
                                                         wqkvT_lo + (size_t)1024 * 1024, 1024, 512, 0, 0);
  tconv_kernel<true><<<dim3(8, 16, 1), 256, 0, stream>>>(wv, wqkvT_hi + (size_t)1536 * 1024,
                                                         wqkvT_lo + (size_t)1536 * 1024, 1024, 512, 0, 0);
  tconv_kernel<true><<<dim3(16, 16, 1), 256, 0, stream>>>(wo, woT_hi, woT_lo, 1024, 1024, 0, 0);

  gemm_kernel<0><<<dim3(16, 16, 1), 256, 0, stream>>>(h_hi, h_lo, wqkvT_hi, wqkvT_lo, qkv, nullptr,
                                                      nullptr, nullptr, nullptr, nullptr, nullptr,
                                                      nullptr, 2048, 1024);
  rope_kernel<<<6144, 256, 0, stream>>>(qkv, sinb, cosb, pos, q_hi, q_lo, k_hi, k_lo);
  vtrans_kernel<<<dim3(32, 8), 256, 0, stream>>>(qkv, vT_hi, vT_lo);
  flash_kernel<<<dim3(32, 16), 256, 0, stream>>>(q_hi, q_lo, k_hi, k_lo, vT_hi, vT_lo, amask, o_hi,
                                                 o_lo);
  gemm_kernel<1><<<dim3(8, 16, 1), 256, 0, stream>>>(o_hi, o_lo, woT_hi, woT_lo, x2, out, nullptr,
                                                     x, nullptr, nullptr, nullptr, nullptr, 1024,
                                                     1024);
  // MoE block
  rmsnorm_kernel<1><<<S, 256, 0, stream>>>(x2, ln2, t, t_bf, nullptr);
  router_kernel<<<S / 4, 256, 0, stream>>>(t, gw, cnt, idxb, wgtb);
  offsets_kernel<<<1, 64, 0, stream>>>(cnt, offs);

  tconv_kernel<false><<<dim3(32, 16, 8), 256, 0, stream>>>(w1, w1T, nullptr, 1024, 2048,
                                                           (long long)1024 * 2048,
                                                           (long long)2048 * 1024);
  tconv_kernel<false><<<dim3(32, 16, 8), 256, 0, stream>>>(w3, w3T, nullptr, 1024, 2048,
                                                           (long long)1024 * 2048,
                                                           (long long)2048 * 1024);
  gemm_kernel<2><<<dim3(16, 16, 8), 256, 0, stream>>>(t_bf, nullptr, w1T, w3T, nullptr, nullptr, G,
                                                      nullptr, idxb, wgtb, cnt, offs, 2048, 1024);
  tconv_kernel<false><<<dim3(16, 32, 8), 256, 0, stream>>>(w2, w2T, nullptr, 2048, 1024,
                                                           (long long)2048 * 1024,
                                                           (long long)1024 * 2048);
  gemm_kernel<3><<<dim3(8, 16, 8), 256, 0, stream>>>(G, nullptr, w2T, nullptr, out, nullptr,
                                                     nullptr, nullptr, idxb, wgtb, cnt, offs, 1024,
                                                     2048);
}

// Round 5
// 470.002 us; speedup vs baseline: 4.1687x; 1.0220x over previous
//
#include <hip/hip_runtime.h>

#define S 2048
#define H 1024
#define NH 16
#define NKV 8
#define HD 64
#define NE 8
#define ID 2048

typedef short bf16x8 __attribute__((ext_vector_type(8)));
typedef short bf16x4 __attribute__((ext_vector_type(4)));
typedef float f32x4 __attribute__((ext_vector_type(4)));

__device__ __forceinline__ unsigned short f2bf(float f) {
  unsigned u = __builtin_bit_cast(unsigned, f);
  u += 0x7FFFu + ((u >> 16) & 1u);
  return (unsigned short)(u >> 16);
}
__device__ __forceinline__ float bf2f(unsigned short h) {
  unsigned u = ((unsigned)h) << 16;
  return __builtin_bit_cast(float, u);
}

typedef const __attribute__((address_space(1))) unsigned int gas_u32;
typedef __attribute__((address_space(3))) unsigned int las_u32;
// direct global->LDS DMA, 16B per lane; LDS dest = wave-uniform base + lane*16
__device__ __forceinline__ void gload16(const unsigned short* g, unsigned short* l) {
  __builtin_amdgcn_global_load_lds((gas_u32*)g, (las_u32*)l, 16, 0, 0);
}

// ---------------- RMSNorm ----------------
// OUTM 0: write hi+lo bf16 planes. OUTM 1: write f32 + hi bf16.
template <int OUTM>
__global__ __launch_bounds__(256) void rmsnorm_kernel(const float* __restrict__ x,
                                                      const float* __restrict__ wgt,
                                                      float* __restrict__ outf,
                                                      unsigned short* __restrict__ ohi,
                                                      unsigned short* __restrict__ olo) {
  int row = blockIdx.x;
  const float* xr = x + (size_t)row * H;
  int tid = threadIdx.x;
  float v[4];
  float ss = 0.f;
#pragma unroll
  for (int i = 0; i < 4; i++) {
    v[i] = xr[tid + i * 256];
    ss += v[i] * v[i];
  }
#pragma unroll
  for (int off = 1; off < 64; off <<= 1) ss += __shfl_xor(ss, off);
  __shared__ float part[4];
  if ((tid & 63) == 0) part[tid >> 6] = ss;
  __syncthreads();
  float tot = part[0] + part[1] + part[2] + part[3];
  float r = rsqrtf(tot * (1.f / H) + 1e-6f);
#pragma unroll
  for (int i = 0; i < 4; i++) {
    int c = tid + i * 256;
    float vv = v[i] * r * wgt[c];
    size_t o = (size_t)row * H + c;
    if (OUTM == 0) {
      unsigned short h_ = f2bf(vv);
      ohi[o] = h_;
      olo[o] = f2bf(vv - bf2f(h_));
    } else {
      outf[o] = vv;
      ohi[o] = f2bf(vv);
    }
  }
}

// ---------------- transpose-convert: src f32 [K][N] -> dst bf16 [N][K] ----------------
template <bool LO>
__global__ __launch_bounds__(256) void tconv_kernel(const float* __restrict__ src,
                                                    unsigned short* __restrict__ hi,
                                                    unsigned short* __restrict__ lo,
                                                    int K, int N, long long sStride,
                                                    long long dStride) {
  int nt = blockIdx.x, kt = blockIdx.y, b = blockIdx.z;
  src += (size_t)b * sStride;
  hi += (size_t)b * dStride;
  if (LO) lo += (size_t)b * dStride;
  __shared__ float tile[64][65];
  int tid = threadIdx.x;
  int r = tid >> 2, cs = (tid & 3) * 16;
  const float* s0 = src + (size_t)(kt * 64 + r) * N + nt * 64 + cs;
#pragma unroll
  for (int i = 0; i < 16; i += 4) {
    float4 a = *(const float4*)(s0 + i);
    tile[r][cs + i] = a.x;
    tile[r][cs + i + 1] = a.y;
    tile[r][cs + i + 2] = a.z;
    tile[r][cs + i + 3] = a.w;
  }
  __syncthreads();
  int n = nt * 64 + r;
  size_t dbase = (size_t)n * K + kt * 64 + cs;
  unsigned short th[16], tl[16];
#pragma unroll
  for (int i = 0; i < 16; i++) {
    float vv = tile[cs + i][r];
    unsigned short h_ = f2bf(vv);
    th[i] = h_;
    if (LO) tl[i] = f2bf(vv - bf2f(h_));
  }
  *(bf16x8*)(hi + dbase) = *(bf16x8*)&th[0];
  *(bf16x8*)(hi + dbase + 8) = *(bf16x8*)&th[8];
  if (LO) {
    *(bf16x8*)(lo + dbase) = *(bf16x8*)&tl[0];
    *(bf16x8*)(lo + dbase + 8) = *(bf16x8*)&tl[8];
  }
}

// ---------------- MFMA GEMM, 128x128 tile, BK=64, gload_lds + XOR swizzle ----------------
// MODE 0: QKV   A=h hi/lo [M][K], B=wqkvT hi/lo [N][K], 3-term split, C=qkv f32
// MODE 1: OPROJ same + resid, dual store (x2 and out)
// MODE 2: MOEA  A=t_bf gathered (tile table grid), Bh=w1T Bl=w3T, silu(g1)*g3 -> G bf16
// MODE 3: MOEB  A=G (tile table grid), B=w2T, atomicAdd out += v*wgt
template <int MODE>
__global__ __launch_bounds__(256) void gemm_kernel(
    const unsigned short* __restrict__ Ah, const unsigned short* __restrict__ Al,
    const unsigned short* __restrict__ Bh, const unsigned short* __restrict__ Bl,
    float* __restrict__ C, float* __restrict__ C2, unsigned short* __restrict__ Gout,
    const float* __restrict__ resid, const int* __restrict__ idx,
    const float* __restrict__ wgt, const int* __restrict__ cnt,
    const int* __restrict__ offs, const int* __restrict__ tmap, int N, int K) {
  int n0 = blockIdx.x * 128, m0, e = 0;
  int ce = 0, gbase = 0;
  if (MODE >= 2) {
    int ntiles = tmap[63];
    if ((int)blockIdx.y >= ntiles) return;
    int packed = tmap[blockIdx.y];
    e = packed >> 16;
    m0 = (packed & 0xffff) * 128;
    ce = cnt[e];
    gbase = offs[e];
  } else {
    m0 = blockIdx.y * 128;
  }
  const unsigned short* bhp = Bh;
  const unsigned short* blp = Bl;
  if (MODE == 2) {
    bhp += (size_t)e * 2048 * 1024;
    blp += (size_t)e * 2048 * 1024;
  }
  if (MODE == 3) bhp += (size_t)e * 1024 * 2048;

  __shared__ __align__(16) unsigned short tAh[128 * 64];
  __shared__ __align__(16) unsigned short tAl[128 * 64];
  __shared__ __align__(16) unsigned short tBh[128 * 64];
  __shared__ __align__(16) unsigned short tBl[128 * 64];

  int tid = threadIdx.x, w = tid >> 6, lane = tid & 63;
  int lr = lane & 15, g = lane >> 4;
  int rloc = lane >> 3, slotg = (lane & 7) ^ rloc;
  int wm = w >> 1, wn = w & 1;

  // per-chunk per-lane source element offsets (k0=0); inverse-swizzled slot
  unsigned aOff[4], bOff[4];
#pragma unroll
  for (int cc = 0; cc < 4; cc++) {
    int rr = w * 32 + cc * 8 + rloc;  // tile-local row 0..127
    bOff[cc] = (unsigned)((n0 + rr) * K + slotg * 8);
    if (MODE == 2) {
      int gr = m0 + rr;
      if (gr > ce - 1) gr = ce - 1;
      int tok = idx[e * S + gr];
      aOff[cc] = (unsigned)(tok * K + slotg * 8);
    } else if (MODE == 3) {
      int gr = gbase + m0 + rr;
      if (gr > 4095) gr = 4095;
      aOff[cc] = (unsigned)(gr * K + slotg * 8);
    } else {
      aOff[cc] = (unsigned)((m0 + rr) * K + slotg * 8);
    }
  }

  f32x4 acc[4][4], acc2[4][4];
#pragma unroll
  for (int i = 0; i < 4; i++)
#pragma unroll
    for (int j = 0; j < 4; j++) {
      acc[i][j] = f32x4{0.f, 0.f, 0.f, 0.f};
      if (MODE == 2) acc2[i][j] = f32x4{0.f, 0.f, 0.f, 0.f};
    }

  for (int k0 = 0; k0 < K; k0 += 64) {
    __syncthreads();
#pragma unroll
    for (int cc = 0; cc < 4; cc++) {
      int cb = (w * 4 + cc) * 512;
      gload16(Ah + aOff[cc] + k0, &tAh[cb]);
      gload16(bhp + bOff[cc] + k0, &tBh[cb]);
      if (MODE <= 1) {
        gload16(Al + aOff[cc] + k0, &tAl[cb]);
        gload16(blp + bOff[cc] + k0, &tBl[cb]);
      }
      if (MODE == 2) gload16(blp + bOff[cc] + k0, &tBl[cb]);
    }
    __syncthreads();
    bf16x8 fah[4][2], fal[4][2];
#pragma unroll
    for (int i = 0; i < 4; i++) {
      int ar = wm * 64 + i * 16 + lr;
#pragma unroll
      for (int kk = 0; kk < 2; kk++) {
        int off = ar * 64 + (((kk * 4 + g) ^ (ar & 7)) * 8);
        fah[i][kk] = *(const bf16x8*)&tAh[off];
        if (MODE <= 1) fal[i][kk] = *(const bf16x8*)&tAl[off];
      }
    }
#pragma unroll
    for (int j = 0; j < 4; j++) {
      int br = wn * 64 + j * 16 + lr;
      bf16x8 fbh[2], fbl[2];
#pragma unroll
      for (int kk = 0; kk < 2; kk++) {
        int off = br * 64 + (((kk * 4 + g) ^ (br & 7)) * 8);
        fbh[kk] = *(const bf16x8*)&tBh[off];
        if (MODE <= 2) fbl[kk] = *(const bf16x8*)&tBl[off];
      }
#pragma unroll
      for (int i = 0; i < 4; i++) {
#pragma unroll
        for (int kk = 0; kk < 2; kk++) {
          acc[i][j] = __builtin_amdgcn_mfma_f32_16x16x32_bf16(fah[i][kk], fbh[kk], acc[i][j], 0, 0, 0);
          if (MODE <= 1) {
            acc[i][j] = __builtin_amdgcn_mfma_f32_16x16x32_bf16(fah[i][kk], fbl[kk], acc[i][j], 0, 0, 0);
            acc[i][j] = __builtin_amdgcn_mfma_f32_16x16x32_bf16(fal[i][kk], fbh[kk], acc[i][j], 0, 0, 0);
          }
          if (MODE == 2)
            acc2[i][j] = __builtin_amdgcn_mfma_f32_16x16x32_bf16(fah[i][kk], fbl[kk], acc2[i][j], 0, 0, 0);
        }
      }
    }
  }
  // epilogue
#pragma unroll
  for (int i = 0; i < 4; i++)
#pragma unroll
    for (int j = 0; j < 4; j++)
#pragma unroll
      for (int r = 0; r < 4; r++) {
        int grow = wm * 64 + i * 16 + g * 4 + r;
        int gcol = n0 + wn * 64 + j * 16 + lr;
        float v = acc[i][j][r];
        if (MODE == 0) {
          C[(size_t)(m0 + grow) * N + gcol] = v;
        } else if (MODE == 1) {
          float o = v + resid[(size_t)(m0 + grow) * N + gcol];
          C[(size_t)(m0 + grow) * N + gcol] = o;
          C2[(size_t)(m0 + grow) * N + gcol] = o;
        } else if (MODE == 2) {
          if (m0 + grow < ce) {
            float g3 = acc2[i][j][r];
            float sg = v / (1.f + __expf(-v));
            Gout[(size_t)(gbase + m0 + grow) * 2048 + gcol] = f2bf(sg * g3);
          }
        } else {
          if (m0 + grow < ce) {
            int tok = idx[e * S + m0 + grow];
            float wv = wgt[e * S + m0 + grow];
            atomicAdd(&C[(size_t)tok * 1024 + gcol], v * wv);
          }
        }
      }
}

// ---------------- RoPE: qkv f32 -> q hi/lo (x0.125), k hi/lo planes ----------------
__global__ __launch_bounds__(256) void rope_kernel(
    const float* __restrict__ qkv, const float* __restrict__ sinb,
    const float* __restrict__ cosb, const int* __restrict__ pos,
    unsigned short* __restrict__ qhi, unsigned short* __restrict__ qlo,
    unsigned short* __restrict__ khi, unsigned short* __restrict__ klo) {
  int i = blockIdx.x * 256 + threadIdx.x;
  int d = i & 31;
  int s = (i >> 5) & 2047;
  int hh = i >> 16;  // 0..23
  int p = pos[s];
  float c0 = cosb[p * HD + d], c1 = cosb[p * HD + d + 32];
  float s0 = sinb[p * HD + d], s1 = sinb[p * HD + d + 32];
  const float* srcb = qkv + (size_t)s * 2048;
  if (hh < NH) {
    float x0 = srcb[hh * HD + d], x1 = srcb[hh * HD + d + 32];
    float r0 = (x0 * c0 - x1 * s0) * 0.125f;
    float r1 = (x1 * c1 + x0 * s1) * 0.125f;
    size_t o = ((size_t)hh * S + s) * HD + d;
    unsigned short h0 = f2bf(r0), h1 = f2bf(r1);
    qhi[o] = h0;
    qlo[o] = f2bf(r0 - bf2f(h0));
    qhi[o + 32] = h1;
    qlo[o + 32] = f2bf(r1 - bf2f(h1));
  } else {
    int hk = hh - NH;
    float x0 = srcb[1024 + hk * HD + d], x1 = srcb[1024 + hk * HD + d + 32];
    float r0 = x0 * c0 - x1 * s0;
    float r1 = x1 * c1 + x0 * s1;
    size_t o = ((size_t)hk * S + s) * HD + d;
    unsigned short h0 = f2bf(r0), h1 = f2bf(r1);
    khi[o] = h0;
    klo[o] = f2bf(r0 - bf2f(h0));
    khi[o + 32] = h1;
    klo[o + 32] = f2bf(r1 - bf2f(h1));
  }
}

// ---------------- V transpose: qkv v-cols -> vT[hk][d][s] hi/lo bf16 ----------------
__global__ __launch_bounds__(256) void vtrans_kernel(const float* __restrict__ qkv,
                                                     unsigned short* __restrict__ vThi,
                                                     unsigned short* __restrict__ vTlo) {
  int st = blockIdx.x, hk = blockIdx.y;
  __shared__ float tile[64][65];
  int tid = threadIdx.x;
  int r = tid >> 2, seg = (tid & 3) * 16;
  const float* src = qkv + (size_t)(st * 64 + r) * 2048 + 1536 + hk * HD + seg;
#pragma unroll
  for (int i = 0; i < 16; i += 4) {
    float4 a = *(const float4*)(src + i);
    tile[r][seg + i] = a.x;
    tile[r][seg + i + 1] = a.y;
    tile[r][seg + i + 2] = a.z;
    tile[r][seg + i + 3] = a.w;
  }
  __syncthreads();
  int d = tid >> 2, ss = (tid & 3) * 16;
  unsigned short th[16], tl[16];
#pragma unroll
  for (int i = 0; i < 16; i++) {
    float vv = tile[ss + i][d];
    unsigned short h_ = f2bf(vv);
    th[i] = h_;
    tl[i] = f2bf(vv - bf2f(h_));
  }
  size_t dst = ((size_t)hk * HD + d) * S + st * 64 + ss;
  *(bf16x8*)(vThi + dst) = *(bf16x8*)&th[0];
  *(bf16x8*)(vThi + dst + 8) = *(bf16x8*)&th[8];
  *(bf16x8*)(vTlo + dst) = *(bf16x8*)&tl[0];
  *(bf16x8*)(vTlo + dst + 8) = *(bf16x8*)&tl[8];
}

// ---------------- flash attention (MFMA, pre-split bf16, gload_lds staging) ----------------
#define FSWZ(row, byteoff) ((byteoff) ^ (((row) & 7) << 4))

__global__ __launch_bounds__(256) void flash_kernel(
    const unsigned short* __restrict__ qhi, const unsigned short* __restrict__ qlo,
    const unsigned short* __restrict__ khip, const unsigned short* __restrict__ klop,
    const unsigned short* __restrict__ vthip, const unsigned short* __restrict__ vtlop,
    const float* __restrict__ amask, unsigned short* __restrict__ ohi,
    unsigned short* __restrict__ olo) {
  int qt = (int)gridDim.x - 1 - (int)blockIdx.x;  // long blocks first
  int head = blockIdx.y;
  int tid = threadIdx.x;
  int w = tid >> 6, lane = tid & 63;
  int lr = lane & 15, g = lane >> 4;
  int rloc = lane >> 3, slotg = (lane & 7) ^ rloc;

  __shared__ __align__(16) unsigned short Khi[64 * 64];
  __shared__ __align__(16) unsigned short Klo[64 * 64];
  __shared__ __align__(16) unsigned short Vhi[64 * 64];
  __shared__ __align__(16) unsigned short Vlo[64 * 64];
  __shared__ __align__(16) unsigned short Phi[4][16 * 64];
  __shared__ __align__(16) unsigned short Plo[4][16 * 64];
  __shared__ unsigned long long vismask;

  int qrow = qt * 64 + w * 16 + lr;
  bf16x8 qh[2], ql[2];
  {
    const unsigned short* qb = qhi + ((size_t)head * S + qrow) * HD;
    const unsigned short* qb2 = qlo + ((size_t)head * S + qrow) * HD;
    qh[0] = *(const bf16x8*)(qb + g * 8);
    qh[1] = *(const bf16x8*)(qb + 32 + g * 8);
    ql[0] = *(const bf16x8*)(qb2 + g * 8);
    ql[1] = *(const bf16x8*)(qb2 + 32 + g * 8);
  }

  f32x4 oacc[4];
#pragma unroll
  for (int dg = 0; dg < 4; dg++) oacc[dg] = f32x4{0.f, 0.f, 0.f, 0.f};
  float m = -1e30f, l = 0.f;

  const unsigned short* kbh = khip + (size_t)(head >> 1) * S * HD;
  const unsigned short* kbl = klop + (size_t)(head >> 1) * S * HD;
  const unsigned short* vbh = vthip + (size_t)(head >> 1) * HD * S;
  const unsigned short* vbl = vtlop + (size_t)(head >> 1) * HD * S;
  char* pbase = (char*)Phi[w];
  char* plbase = (char*)Plo[w];

  for (int kb = 0; kb <= qt; kb++) {
    int kv0 = kb * 64;
    __syncthreads();
#pragma unroll
    for (int cc = 0; cc < 2; cc++) {
      int c = w * 2 + cc;
      int r = c * 8 + rloc;
      gload16(kbh + (size_t)(kv0 + r) * HD + slotg * 8, &Khi[c * 512]);
      gload16(kbl + (size_t)(kv0 + r) * HD + slotg * 8, &Klo[c * 512]);
      gload16(vbh + (size_t)r * S + kv0 + slotg * 8, &Vhi[c * 512]);
      gload16(vbl + (size_t)r * S + kv0 + slotg * 8, &Vlo[c * 512]);
    }
    if (tid < 64) {
      unsigned long long bm = __ballot(amask[kv0 + tid] > 0.f);
      if (tid == 0) vismask = bm;
    }
    __syncthreads();
    unsigned long long vm = vismask;

    // ---- QK^T (S^T): lane -> q-row lr, kv = c*16 + 4*g + r ----
    f32x4 sacc[4];
#pragma unroll
    for (int c = 0; c < 4; c++) sacc[c] = f32x4{0.f, 0.f, 0.f, 0.f};
#pragma unroll
    for (int c = 0; c < 4; c++) {
#pragma unroll
      for (int kc = 0; kc < 2; kc++) {
        int row = c * 16 + lr;
        int bo = FSWZ(row, row * 128 + kc * 64 + g * 16);
        bf16x8 khf = *(const bf16x8*)((char*)Khi + bo);
        bf16x8 klf = *(const bf16x8*)((char*)Klo + bo);
        sacc[c] = __builtin_amdgcn_mfma_f32_16x16x32_bf16(khf, qh[kc], sacc[c], 0, 0, 0);
        sacc[c] = __builtin_amdgcn_mfma_f32_16x16x32_bf16(khf, ql[kc], sacc[c], 0, 0, 0);
        sacc[c] = __builtin_amdgcn_mfma_f32_16x16x32_bf16(klf, qh[kc], sacc[c], 0, 0, 0);
      }
    }
    // ---- mask + online softmax ----
    int qloc = w * 16 + lr;
    bool diag = (kb == qt);
    float tm = -1e30f;
#pragma unroll
    for (int c = 0; c < 4; c++) {
#pragma unroll
      for (int r = 0; r < 4; r++) {
        int kvloc = c * 16 + 4 * g + r;
        bool vis = ((vm >> kvloc) & 1ull) && (!diag || kvloc <= qloc);
        float sv = vis ? sacc[c][r] : -1e30f;
        sacc[c][r] = sv;
        tm = fmaxf(tm, sv);
      }
    }
    tm = fmaxf(tm, __shfl_xor(tm, 16));
    tm = fmaxf(tm, __shfl_xor(tm, 32));
    float newm = fmaxf(m, tm);
    float alpha = __expf(m - newm);
    float rs = 0.f;
#pragma unroll
    for (int c = 0; c < 4; c++) {
#pragma unroll
      for (int r = 0; r < 4; r++) {
        float p = __expf(sacc[c][r] - newm);
        sacc[c][r] = p;
        rs += p;
      }
    }
    rs += __shfl_xor(rs, 16);
    rs += __shfl_xor(rs, 32);
    m = newm;
    l = l * alpha + rs;
#pragma unroll
    for (int dg = 0; dg < 4; dg++) {
#pragma unroll
      for (int r = 0; r < 4; r++) oacc[dg][r] *= alpha;
    }
    // ---- write P hi/lo to per-wave LDS ----
#pragma unroll
    for (int c = 0; c < 4; c++) {
      bf16x4 ph, pl2;
#pragma unroll
      for (int r = 0; r < 4; r++) {
        float pv = sacc[c][r];
        unsigned short h_ = f2bf(pv);
        ph[r] = (short)h_;
        pl2[r] = (short)f2bf(pv - bf2f(h_));
      }
      int bo = FSWZ(lr, lr * 128 + (c * 16 + 4 * g) * 2);
      *(bf16x4*)(pbase + bo) = ph;
      *(bf16x4*)(plbase + bo) = pl2;
    }
    // ---- PV: O^T += V^T * P^T ----
    bf16x8 pbh[2], pbl[2];
#pragma unroll
    for (int kc = 0; kc < 2; kc++) {
      int bo = FSWZ(lr, lr * 128 + kc * 64 + g * 16);
      pbh[kc] = *(const bf16x8*)(pbase + bo);
      pbl[kc] = *(const bf16x8*)(plbase + bo);
    }
#pragma unroll
    for (int dg = 0; dg < 4; dg++) {
#pragma unroll
      for (int kc = 0; kc < 2; kc++) {
        int row = dg * 16 + lr;
        int bo = FSWZ(row, row * 128 + kc * 64 + g * 16);
        bf16x8 vhf = *(const bf16x8*)((char*)Vhi + bo);
        bf16x8 vlf = *(const bf16x8*)((char*)Vlo + bo);
        oacc[dg] = __builtin_amdgcn_mfma_f32_16x16x32_bf16(vhf, pbh[kc], oacc[dg], 0, 0, 0);
        oacc[dg] = __builtin_amdgcn_mfma_f32_16x16x32_bf16(vhf, pbl[kc], oacc[dg], 0, 0, 0);
        oacc[dg] = __builtin_amdgcn_mfma_f32_16x16x32_bf16(vlf, pbh[kc], oacc[dg], 0, 0, 0);
      }
    }
  }

  float inv = 1.f / l;
  size_t ob = (size_t)qrow * 1024 + head * HD;
#pragma unroll
  for (int dg = 0; dg < 4; dg++) {
    bf16x4 th, tl;
#pragma unroll
    for (int r = 0; r < 4; r++) {
      float vv = oacc[dg][r] * inv;
      unsigned short h_ = f2bf(vv);
      th[r] = (short)h_;
      tl[r] = (short)f2bf(vv - bf2f(h_));
    }
    *(bf16x4*)(ohi + ob + dg * 16 + 4 * g) = th;
    *(bf16x4*)(olo + ob + dg * 16 + 4 * g) = tl;
  }
}

// ---------------- router ----------------
__global__ __launch_bounds__(256) void router_kernel(const float* __restrict__ t,
                                                     const float* __restrict__ gw,
                                                     int* __restrict__ cnt,
                                                     int* __restrict__ idxb,
                                                     float* __restrict__ wgtb) {
  int tok = blockIdx.x * 4 + (threadIdx.x >> 6);
  int lane = threadIdx.x & 63;
  const float* tr = t + (size_t)tok * H;
  float acc[NE];
#pragma unroll
  for (int e = 0; e < NE; e++) acc[e] = 0.f;
#pragma unroll
  for (int i = 0; i < 16; i++) {
    float tv = tr[lane * 16 + i];
    const float* g = gw + (size_t)(lane * 16 + i) * NE;
#pragma unroll
    for (int e = 0; e < NE; e++) acc[e] += tv * g[e];
  }
#pragma unroll
  for (int off = 1; off < 64; off <<= 1) {
#pragma unroll
    for (int e = 0; e < NE; e++) acc[e] += __shfl_xor(acc[e], off);
  }
  if (lane == 0) {
    int e1 = 0;
#pragma unroll
    for (int e = 1; e < NE; e++)
      if (acc[e] > acc[e1]) e1 = e;
    int e2 = -1;
#pragma unroll
    for (int e = 0; e < NE; e++)
      if (e != e1 && (e2 < 0 || acc[e] > acc[e2])) e2 = e;
    float w1v = 1.f / (1.f + __expf(acc[e2] - acc[e1]));
    float w2v = 1.f - w1v;
    int p1 = atomicAdd(&cnt[e1], 1);
    idxb[e1 * S + p1] = tok;
    wgtb[e1 * S + p1] = w1v;
    int p2 = atomicAdd(&cnt[e2], 1);
    idxb[e2 * S + p2] = tok;
    wgtb[e2 * S + p2] = w2v;
  }
}

// prefix offsets + dense tile table: tmap[t] = (expert<<16) | m_tile, tmap[63] = count
__global__ void offsets_kernel(const int* __restrict__ cnt, int* __restrict__ offs,
                               int* __restrict__ tmap) {
  if (threadIdx.x == 0 && blockIdx.x == 0) {
    int a = 0, t = 0;
    for (int e = 0; e < NE; e++) {
      offs[e] = a;
      a += cnt[e];
      int nt = (cnt[e] + 127) >> 7;
      for (int i = 0; i < nt; i++) tmap[t++] = (e << 16) | i;
    }
    offs[NE] = a;
    tmap[63] = t;  // t <= 40
  }
}

// ---------------- launch ----------------
extern "C" void kernel_launch(void* const* d_in, const int* in_sizes, int n_in,
                              void* d_out, int out_size, void* d_ws, size_t ws_size,
                              hipStream_t stream) {
  const float* x = (const float*)d_in[0];
  const float* amask = (const float*)d_in[1];
  const int* pos = (const int*)d_in[2];
  const float* sinb = (const float*)d_in[3];
  const float* cosb = (const float*)d_in[4];
  const float* wq = (const float*)d_in[5];
  const float* wk = (const float*)d_in[6];
  const float* wv = (const float*)d_in[7];
  const float* wo = (const float*)d_in[8];
  const float* ln1 = (const float*)d_in[9];
  const float* ln2 = (const float*)d_in[10];
  const float* gw = (const float*)d_in[11];
  const float* w1 = (const float*)d_in[12];
  const float* w3 = (const float*)d_in[13];
  const float* w2 = (const float*)d_in[14];
  float* out = (float*)d_out;

  char* ws = (char*)d_ws;
  const size_t MB = 1024 * 1024;
  // persistent
  float* x2 = (float*)(ws + 0 * MB);                    // 8 MB
  unsigned short* t_bf = (unsigned short*)(ws + 8 * MB);  // 4 MB
  int* cnt = (int*)(ws + 12 * MB);
  int* offs = cnt + 16;
  int* tmap = cnt + 32;            // 64 ints
  int* idxb = cnt + 128;
  float* wgtb = (float*)(idxb + NE * S);
  // MoE region
  unsigned short* G = (unsigned short*)(ws + 13 * MB);    // 16 MB: 13-29
  unsigned short* w1T = (unsigned short*)(ws + 29 * MB);  // 32 MB: 29-61
  unsigned short* w3T = (unsigned short*)(ws + 61 * MB);  // 32 MB: 61-93
  unsigned short* w2T = (unsigned short*)(ws + 29 * MB);  // reuse after mode2
  // phase-1 overlays (dead before MoE tconvs run)
  float* qkv = (float*)(ws + 13 * MB);                       // 16 MB: 13-29
  unsigned short* wqkvT_hi = (unsigned short*)(ws + 29 * MB);  // 4 MB
  unsigned short* wqkvT_lo = (unsigned short*)(ws + 33 * MB);  // 4 MB
  unsigned short* woT_hi = (unsigned short*)(ws + 37 * MB);    // 2 MB
  unsigned short* woT_lo = (unsigned short*)(ws + 39 * MB);    // 2 MB
  unsigned short* h_hi = (unsigned short*)(ws + 41 * MB);      // 4 MB
  unsigned short* h_lo = (unsigned short*)(ws + 45 * MB);      // 4 MB
  unsigned short* q_hi = (unsigned short*)(ws + 49 * MB);      // 4 MB
  unsigned short* q_lo = (unsigned short*)(ws + 53 * MB);      // 4 MB
  unsigned short* k_hi = (unsigned short*)(ws + 57 * MB);      // 2 MB
  unsigned short* k_lo = (unsigned short*)(ws + 59 * MB);      // 2 MB
  unsigned short* vT_hi = (unsigned short*)(ws + 61 * MB);     // 2 MB
  unsigned short* vT_lo = (unsigned short*)(ws + 63 * MB);     // 2 MB
  unsigned short* o_hi = (unsigned short*)(ws + 65 * MB);      // 4 MB
  unsigned short* o_lo = (unsigned short*)(ws + 69 * MB);      // 4 MB
  float* t = (float*)(ws + 73 * MB);                           // 8 MB: 73-81

  hipMemsetAsync(cnt, 0, 16 * sizeof(int), stream);

  // attention block
  rmsnorm_kernel<0><<<S, 256, 0, stream>>>(x, ln1, nullptr, h_hi, h_lo);
  tconv_kernel<true><<<dim3(16, 16, 1), 256, 0, stream>>>(wq, wqkvT_hi, wqkvT_lo, 1024, 1024, 0, 0);
  tconv_kernel<true><<<dim3(8, 16, 1), 256, 0, stream>>>(wk, wqkvT_hi + (size_t)1024 * 1024,
                                                         wqkvT_lo + (size_t)1024 * 1024, 1024, 512, 0, 0);
  tconv_kernel<true><<<dim3(8, 16, 1), 256, 0, stream>>>(wv, wqkvT_hi + (size_t)1536 * 1024,
                                                         wqkvT_lo + (size_t)1536 * 1024, 1024, 512, 0, 0);
  tconv_kernel<true><<<dim3(16, 16, 1), 256, 0, stream>>>(wo, woT_hi, woT_lo, 1024, 1024, 0, 0);

  gemm_kernel<0><<<dim3(16, 16, 1), 256, 0, stream>>>(h_hi, h_lo, wqkvT_hi, wqkvT_lo, qkv, nullptr,
                                                      nullptr, nullptr, nullptr, nullptr, nullptr,
                                                      nullptr, nullptr, 2048, 1024);
  rope_kernel<<<6144, 256, 0, stream>>>(qkv, sinb, cosb, pos, q_hi, q_lo, k_hi, k_lo);
  vtrans_kernel<<<dim3(32, 8), 256, 0, stream>>>(qkv, vT_hi, vT_lo);
  flash_kernel<<<dim3(32, 16), 256, 0, stream>>>(q_hi, q_lo, k_hi, k_lo, vT_hi, vT_lo, amask, o_hi,
                                                 o_lo);
  gemm_kernel<1><<<dim3(8, 16, 1), 256, 0, stream>>>(o_hi, o_lo, woT_hi, woT_lo, x2, out, nullptr,
                                                     x, nullptr, nullptr, nullptr, nullptr,
                                                     nullptr, 1024, 1024);
  // MoE block
  rmsnorm_kernel<1><<<S, 256, 0, stream>>>(x2, ln2, t, t_bf, nullptr);
  router_kernel<<<S / 4, 256, 0, stream>>>(t, gw, cnt, idxb, wgtb);
  offsets_kernel<<<1, 64, 0, stream>>>(cnt, offs, tmap);

  tconv_kernel<false><<<dim3(32, 16, 8), 256, 0, stream>>>(w1, w1T, nullptr, 1024, 2048,
                                                           (long long)1024 * 2048,
                                                           (long long)2048 * 1024);
  tconv_kernel<false><<<dim3(32, 16, 8), 256, 0, stream>>>(w3, w3T, nullptr, 1024, 2048,
                                                           (long long)1024 * 2048,
                                                           (long long)2048 * 1024);
  gemm_kernel<2><<<dim3(16, 40, 1), 256, 0, stream>>>(t_bf, nullptr, w1T, w3T, nullptr, nullptr, G,
                                                      nullptr, idxb, wgtb, cnt, offs, tmap, 2048,
                                                      1024);
  tconv_kernel<false><<<dim3(16, 32, 8), 256, 0, stream>>>(w2, w2T, nullptr, 2048, 1024,
                                                           (long long)2048 * 1024,
                                                           (long long)1024 * 2048);
  gemm_kernel<3><<<dim3(8, 40, 1), 256, 0, stream>>>(G, nullptr, w2T, nullptr, out, nullptr,
                                                     nullptr, nullptr, idxb, wgtb, cnt, offs, tmap,
                                                     1024, 2048);
}

// Round 6
// 391.504 us; speedup vs baseline: 5.0046x; 1.2005x over previous
//
#include <hip/hip_runtime.h>

#define S 2048
#define H 1024
#define NH 16
#define NKV 8
#define HD 64
#define NE 8
#define ID 2048

typedef short bf16x8 __attribute__((ext_vector_type(8)));
typedef short bf16x4 __attribute__((ext_vector_type(4)));
typedef float f32x4 __attribute__((ext_vector_type(4)));

__device__ __forceinline__ unsigned short f2bf(float f) {
  unsigned u = __builtin_bit_cast(unsigned, f);
  u += 0x7FFFu + ((u >> 16) & 1u);
  return (unsigned short)(u >> 16);
}
__device__ __forceinline__ float bf2f(unsigned short h) {
  unsigned u = ((unsigned)h) << 16;
  return __builtin_bit_cast(float, u);
}

typedef const __attribute__((address_space(1))) unsigned int gas_u32;
typedef __attribute__((address_space(3))) unsigned int las_u32;
// direct global->LDS DMA, 16B per lane; LDS dest = wave-uniform base + lane*16
__device__ __forceinline__ void gload16(const unsigned short* g, unsigned short* l) {
  __builtin_amdgcn_global_load_lds((gas_u32*)g, (las_u32*)l, 16, 0, 0);
}

// ---------------- RMSNorm ----------------
// OUTM 0: write hi+lo bf16 planes. OUTM 1: write f32 + hi bf16.
template <int OUTM>
__global__ __launch_bounds__(256) void rmsnorm_kernel(const float* __restrict__ x,
                                                      const float* __restrict__ wgt,
                                                      float* __restrict__ outf,
                                                      unsigned short* __restrict__ ohi,
                                                      unsigned short* __restrict__ olo) {
  int row = blockIdx.x;
  const float* xr = x + (size_t)row * H;
  int tid = threadIdx.x;
  float v[4];
  float ss = 0.f;
#pragma unroll
  for (int i = 0; i < 4; i++) {
    v[i] = xr[tid + i * 256];
    ss += v[i] * v[i];
  }
#pragma unroll
  for (int off = 1; off < 64; off <<= 1) ss += __shfl_xor(ss, off);
  __shared__ float part[4];
  if ((tid & 63) == 0) part[tid >> 6] = ss;
  __syncthreads();
  float tot = part[0] + part[1] + part[2] + part[3];
  float r = rsqrtf(tot * (1.f / H) + 1e-6f);
#pragma unroll
  for (int i = 0; i < 4; i++) {
    int c = tid + i * 256;
    float vv = v[i] * r * wgt[c];
    size_t o = (size_t)row * H + c;
    if (OUTM == 0) {
      unsigned short h_ = f2bf(vv);
      ohi[o] = h_;
      olo[o] = f2bf(vv - bf2f(h_));
    } else {
      outf[o] = vv;
      ohi[o] = f2bf(vv);
    }
  }
}

// ---------------- transpose-convert: src f32 [K][N] -> dst bf16 [N][K] ----------------
template <bool LO>
__global__ __launch_bounds__(256) void tconv_kernel(const float* __restrict__ src,
                                                    unsigned short* __restrict__ hi,
                                                    unsigned short* __restrict__ lo,
                                                    int K, int N, long long sStride,
                                                    long long dStride) {
  int nt = blockIdx.x, kt = blockIdx.y, b = blockIdx.z;
  src += (size_t)b * sStride;
  hi += (size_t)b * dStride;
  if (LO) lo += (size_t)b * dStride;
  __shared__ float tile[64][65];
  int tid = threadIdx.x;
  int r = tid >> 2, cs = (tid & 3) * 16;
  const float* s0 = src + (size_t)(kt * 64 + r) * N + nt * 64 + cs;
#pragma unroll
  for (int i = 0; i < 16; i += 4) {
    float4 a = *(const float4*)(s0 + i);
    tile[r][cs + i] = a.x;
    tile[r][cs + i + 1] = a.y;
    tile[r][cs + i + 2] = a.z;
    tile[r][cs + i + 3] = a.w;
  }
  __syncthreads();
  int n = nt * 64 + r;
  size_t dbase = (size_t)n * K + kt * 64 + cs;
  unsigned short th[16], tl[16];
#pragma unroll
  for (int i = 0; i < 16; i++) {
    float vv = tile[cs + i][r];
    unsigned short h_ = f2bf(vv);
    th[i] = h_;
    if (LO) tl[i] = f2bf(vv - bf2f(h_));
  }
  *(bf16x8*)(hi + dbase) = *(bf16x8*)&th[0];
  *(bf16x8*)(hi + dbase + 8) = *(bf16x8*)&th[8];
  if (LO) {
    *(bf16x8*)(lo + dbase) = *(bf16x8*)&tl[0];
    *(bf16x8*)(lo + dbase + 8) = *(bf16x8*)&tl[8];
  }
}

// ---------------- MFMA GEMM, 128x64 tile, BK=64, gload_lds + XOR swizzle ----------------
// MODE 0: QKV   A=h hi/lo [M][K], B=wqkvT hi/lo [N][K], 3-term split, C=qkv f32
// MODE 1: OPROJ same + resid, dual store (x2 and out)
// MODE 2: MOEA  A=t_bf gathered (tile table grid), Bh=w1T Bl=w3T, silu(g1)*g3 -> G bf16
// MODE 3: MOEB  A=G (tile table grid), B=w2T, atomicAdd out += v*wgt
template <int MODE>
__global__ __launch_bounds__(256) void gemm_kernel(
    const unsigned short* __restrict__ Ah, const unsigned short* __restrict__ Al,
    const unsigned short* __restrict__ Bh, const unsigned short* __restrict__ Bl,
    float* __restrict__ C, float* __restrict__ C2, unsigned short* __restrict__ Gout,
    const float* __restrict__ resid, const int* __restrict__ idx,
    const float* __restrict__ wgt, const int* __restrict__ cnt,
    const int* __restrict__ offs, const int* __restrict__ tmap, int N, int K) {
  int n0 = blockIdx.x * 64, m0, e = 0;
  int ce = 0, gbase = 0;
  if (MODE >= 2) {
    int ntiles = tmap[63];
    if ((int)blockIdx.y >= ntiles) return;
    int packed = tmap[blockIdx.y];
    e = packed >> 16;
    m0 = (packed & 0xffff) * 128;
    ce = cnt[e];
    gbase = offs[e];
  } else {
    m0 = blockIdx.y * 128;
  }
  const unsigned short* bhp = Bh;
  const unsigned short* blp = Bl;
  if (MODE == 2) {
    bhp += (size_t)e * 2048 * 1024;
    blp += (size_t)e * 2048 * 1024;
  }
  if (MODE == 3) bhp += (size_t)e * 1024 * 2048;

  __shared__ __align__(16) unsigned short tAh[128 * 64];
  __shared__ __align__(16) unsigned short tAl[128 * 64];
  __shared__ __align__(16) unsigned short tBh[64 * 64];
  __shared__ __align__(16) unsigned short tBl[64 * 64];

  int tid = threadIdx.x, w = tid >> 6, lane = tid & 63;
  int lr = lane & 15, g = lane >> 4;
  int rloc = lane >> 3, slotg = (lane & 7) ^ rloc;
  int wm = w >> 1, wn = w & 1;

  // per-chunk per-lane source element offsets (k0=0); inverse-swizzled slot
  unsigned aOff[4], bOff[2];
#pragma unroll
  for (int cc = 0; cc < 4; cc++) {
    int rr = w * 32 + cc * 8 + rloc;  // tile-local row 0..127
    if (MODE == 2) {
      int gr = m0 + rr;
      if (gr > ce - 1) gr = ce - 1;
      int tok = idx[e * S + gr];
      aOff[cc] = (unsigned)(tok * K + slotg * 8);
    } else if (MODE == 3) {
      int gr = gbase + m0 + rr;
      if (gr > 4095) gr = 4095;
      aOff[cc] = (unsigned)(gr * K + slotg * 8);
    } else {
      aOff[cc] = (unsigned)((m0 + rr) * K + slotg * 8);
    }
  }
#pragma unroll
  for (int cc = 0; cc < 2; cc++) {
    int rr = w * 16 + cc * 8 + rloc;  // tile-local n-row 0..63
    bOff[cc] = (unsigned)((n0 + rr) * K + slotg * 8);
  }

  f32x4 acc[4][2], acc2[4][2];
#pragma unroll
  for (int i = 0; i < 4; i++)
#pragma unroll
    for (int j = 0; j < 2; j++) {
      acc[i][j] = f32x4{0.f, 0.f, 0.f, 0.f};
      if (MODE == 2) acc2[i][j] = f32x4{0.f, 0.f, 0.f, 0.f};
    }

  for (int k0 = 0; k0 < K; k0 += 64) {
    __syncthreads();
#pragma unroll
    for (int cc = 0; cc < 4; cc++) {
      int cb = (w * 4 + cc) * 512;
      gload16(Ah + aOff[cc] + k0, &tAh[cb]);
      if (MODE <= 1) gload16(Al + aOff[cc] + k0, &tAl[cb]);
    }
#pragma unroll
    for (int cc = 0; cc < 2; cc++) {
      int cb = (w * 2 + cc) * 512;
      gload16(bhp + bOff[cc] + k0, &tBh[cb]);
      if (MODE <= 2) gload16(blp + bOff[cc] + k0, &tBl[cb]);
    }
    __syncthreads();
    bf16x8 fah[4][2], fal[4][2];
#pragma unroll
    for (int i = 0; i < 4; i++) {
      int ar = wm * 64 + i * 16 + lr;
#pragma unroll
      for (int kk = 0; kk < 2; kk++) {
        int off = ar * 64 + (((kk * 4 + g) ^ (ar & 7)) * 8);
        fah[i][kk] = *(const bf16x8*)&tAh[off];
        if (MODE <= 1) fal[i][kk] = *(const bf16x8*)&tAl[off];
      }
    }
#pragma unroll
    for (int j = 0; j < 2; j++) {
      int br = wn * 32 + j * 16 + lr;
      bf16x8 fbh[2], fbl[2];
#pragma unroll
      for (int kk = 0; kk < 2; kk++) {
        int off = br * 64 + (((kk * 4 + g) ^ (br & 7)) * 8);
        fbh[kk] = *(const bf16x8*)&tBh[off];
        if (MODE <= 2) fbl[kk] = *(const bf16x8*)&tBl[off];
      }
#pragma unroll
      for (int i = 0; i < 4; i++) {
#pragma unroll
        for (int kk = 0; kk < 2; kk++) {
          acc[i][j] = __builtin_amdgcn_mfma_f32_16x16x32_bf16(fah[i][kk], fbh[kk], acc[i][j], 0, 0, 0);
          if (MODE <= 1) {
            acc[i][j] = __builtin_amdgcn_mfma_f32_16x16x32_bf16(fah[i][kk], fbl[kk], acc[i][j], 0, 0, 0);
            acc[i][j] = __builtin_amdgcn_mfma_f32_16x16x32_bf16(fal[i][kk], fbh[kk], acc[i][j], 0, 0, 0);
          }
          if (MODE == 2)
            acc2[i][j] = __builtin_amdgcn_mfma_f32_16x16x32_bf16(fah[i][kk], fbl[kk], acc2[i][j], 0, 0, 0);
        }
      }
    }
  }
  // epilogue
#pragma unroll
  for (int i = 0; i < 4; i++)
#pragma unroll
    for (int j = 0; j < 2; j++)
#pragma unroll
      for (int r = 0; r < 4; r++) {
        int grow = wm * 64 + i * 16 + g * 4 + r;
        int gcol = n0 + wn * 32 + j * 16 + lr;
        float v = acc[i][j][r];
        if (MODE == 0) {
          C[(size_t)(m0 + grow) * N + gcol] = v;
        } else if (MODE == 1) {
          float o = v + resid[(size_t)(m0 + grow) * N + gcol];
          C[(size_t)(m0 + grow) * N + gcol] = o;
          C2[(size_t)(m0 + grow) * N + gcol] = o;
        } else if (MODE == 2) {
          if (m0 + grow < ce) {
            float g3 = acc2[i][j][r];
            float sg = v / (1.f + __expf(-v));
            Gout[(size_t)(gbase + m0 + grow) * 2048 + gcol] = f2bf(sg * g3);
          }
        } else {
          if (m0 + grow < ce) {
            int tok = idx[e * S + m0 + grow];
            float wv = wgt[e * S + m0 + grow];
            atomicAdd(&C[(size_t)tok * 1024 + gcol], v * wv);
          }
        }
      }
}

// ---------------- RoPE: qkv f32 -> q hi/lo (x0.125), k hi/lo planes ----------------
__global__ __launch_bounds__(256) void rope_kernel(
    const float* __restrict__ qkv, const float* __restrict__ sinb,
    const float* __restrict__ cosb, const int* __restrict__ pos,
    unsigned short* __restrict__ qhi, unsigned short* __restrict__ qlo,
    unsigned short* __restrict__ khi, unsigned short* __restrict__ klo) {
  int i = blockIdx.x * 256 + threadIdx.x;
  int d = i & 31;
  int s = (i >> 5) & 2047;
  int hh = i >> 16;  // 0..23
  int p = pos[s];
  float c0 = cosb[p * HD + d], c1 = cosb[p * HD + d + 32];
  float s0 = sinb[p * HD + d], s1 = sinb[p * HD + d + 32];
  const float* srcb = qkv + (size_t)s * 2048;
  if (hh < NH) {
    float x0 = srcb[hh * HD + d], x1 = srcb[hh * HD + d + 32];
    float r0 = (x0 * c0 - x1 * s0) * 0.125f;
    float r1 = (x1 * c1 + x0 * s1) * 0.125f;
    size_t o = ((size_t)hh * S + s) * HD + d;
    unsigned short h0 = f2bf(r0), h1 = f2bf(r1);
    qhi[o] = h0;
    qlo[o] = f2bf(r0 - bf2f(h0));
    qhi[o + 32] = h1;
    qlo[o + 32] = f2bf(r1 - bf2f(h1));
  } else {
    int hk = hh - NH;
    float x0 = srcb[1024 + hk * HD + d], x1 = srcb[1024 + hk * HD + d + 32];
    float r0 = x0 * c0 - x1 * s0;
    float r1 = x1 * c1 + x0 * s1;
    size_t o = ((size_t)hk * S + s) * HD + d;
    unsigned short h0 = f2bf(r0), h1 = f2bf(r1);
    khi[o] = h0;
    klo[o] = f2bf(r0 - bf2f(h0));
    khi[o + 32] = h1;
    klo[o + 32] = f2bf(r1 - bf2f(h1));
  }
}

// ---------------- V transpose: qkv v-cols -> vT[hk][d][s] hi/lo bf16 ----------------
__global__ __launch_bounds__(256) void vtrans_kernel(const float* __restrict__ qkv,
                                                     unsigned short* __restrict__ vThi,
                                                     unsigned short* __restrict__ vTlo) {
  int st = blockIdx.x, hk = blockIdx.y;
  __shared__ float tile[64][65];
  int tid = threadIdx.x;
  int r = tid >> 2, seg = (tid & 3) * 16;
  const float* src = qkv + (size_t)(st * 64 + r) * 2048 + 1536 + hk * HD + seg;
#pragma unroll
  for (int i = 0; i < 16; i += 4) {
    float4 a = *(const float4*)(src + i);
    tile[r][seg + i] = a.x;
    tile[r][seg + i + 1] = a.y;
    tile[r][seg + i + 2] = a.z;
    tile[r][seg + i + 3] = a.w;
  }
  __syncthreads();
  int d = tid >> 2, ss = (tid & 3) * 16;
  unsigned short th[16], tl[16];
#pragma unroll
  for (int i = 0; i < 16; i++) {
    float vv = tile[ss + i][d];
    unsigned short h_ = f2bf(vv);
    th[i] = h_;
    tl[i] = f2bf(vv - bf2f(h_));
  }
  size_t dst = ((size_t)hk * HD + d) * S + st * 64 + ss;
  *(bf16x8*)(vThi + dst) = *(bf16x8*)&th[0];
  *(bf16x8*)(vThi + dst + 8) = *(bf16x8*)&th[8];
  *(bf16x8*)(vTlo + dst) = *(bf16x8*)&tl[0];
  *(bf16x8*)(vTlo + dst + 8) = *(bf16x8*)&tl[8];
}

// ---------------- flash attention (MFMA, pre-split bf16, gload_lds staging) ----------------
#define FSWZ(row, byteoff) ((byteoff) ^ (((row) & 7) << 4))

__global__ __launch_bounds__(256) void flash_kernel(
    const unsigned short* __restrict__ qhi, const unsigned short* __restrict__ qlo,
    const unsigned short* __restrict__ khip, const unsigned short* __restrict__ klop,
    const unsigned short* __restrict__ vthip, const unsigned short* __restrict__ vtlop,
    const float* __restrict__ amask, unsigned short* __restrict__ ohi,
    unsigned short* __restrict__ olo) {
  int qt = (int)gridDim.x - 1 - (int)blockIdx.x;  // long blocks first
  int head = blockIdx.y;
  int tid = threadIdx.x;
  int w = tid >> 6, lane = tid & 63;
  int lr = lane & 15, g = lane >> 4;
  int rloc = lane >> 3, slotg = (lane & 7) ^ rloc;

  __shared__ __align__(16) unsigned short Khi[64 * 64];
  __shared__ __align__(16) unsigned short Klo[64 * 64];
  __shared__ __align__(16) unsigned short Vhi[64 * 64];
  __shared__ __align__(16) unsigned short Vlo[64 * 64];
  __shared__ __align__(16) unsigned short Phi[4][16 * 64];
  __shared__ __align__(16) unsigned short Plo[4][16 * 64];
  __shared__ unsigned long long vismask;

  int qrow = qt * 64 + w * 16 + lr;
  bf16x8 qh[2], ql[2];
  {
    const unsigned short* qb = qhi + ((size_t)head * S + qrow) * HD;
    const unsigned short* qb2 = qlo + ((size_t)head * S + qrow) * HD;
    qh[0] = *(const bf16x8*)(qb + g * 8);
    qh[1] = *(const bf16x8*)(qb + 32 + g * 8);
    ql[0] = *(const bf16x8*)(qb2 + g * 8);
    ql[1] = *(const bf16x8*)(qb2 + 32 + g * 8);
  }

  f32x4 oacc[4];
#pragma unroll
  for (int dg = 0; dg < 4; dg++) oacc[dg] = f32x4{0.f, 0.f, 0.f, 0.f};
  float m = -1e30f, l = 0.f;

  const unsigned short* kbh = khip + (size_t)(head >> 1) * S * HD;
  const unsigned short* kbl = klop + (size_t)(head >> 1) * S * HD;
  const unsigned short* vbh = vthip + (size_t)(head >> 1) * HD * S;
  const unsigned short* vbl = vtlop + (size_t)(head >> 1) * HD * S;
  char* pbase = (char*)Phi[w];
  char* plbase = (char*)Plo[w];

  for (int kb = 0; kb <= qt; kb++) {
    int kv0 = kb * 64;
    __syncthreads();
#pragma unroll
    for (int cc = 0; cc < 2; cc++) {
      int c = w * 2 + cc;
      int r = c * 8 + rloc;
      gload16(kbh + (size_t)(kv0 + r) * HD + slotg * 8, &Khi[c * 512]);
      gload16(kbl + (size_t)(kv0 + r) * HD + slotg * 8, &Klo[c * 512]);
      gload16(vbh + (size_t)r * S + kv0 + slotg * 8, &Vhi[c * 512]);
      gload16(vbl + (size_t)r * S + kv0 + slotg * 8, &Vlo[c * 512]);
    }
    if (tid < 64) {
      unsigned long long bm = __ballot(amask[kv0 + tid] > 0.f);
      if (tid == 0) vismask = bm;
    }
    __syncthreads();
    unsigned long long vm = vismask;

    // ---- QK^T (S^T): lane -> q-row lr, kv = c*16 + 4*g + r ----
    f32x4 sacc[4];
#pragma unroll
    for (int c = 0; c < 4; c++) sacc[c] = f32x4{0.f, 0.f, 0.f, 0.f};
#pragma unroll
    for (int c = 0; c < 4; c++) {
#pragma unroll
      for (int kc = 0; kc < 2; kc++) {
        int row = c * 16 + lr;
        int bo = FSWZ(row, row * 128 + kc * 64 + g * 16);
        bf16x8 khf = *(const bf16x8*)((char*)Khi + bo);
        bf16x8 klf = *(const bf16x8*)((char*)Klo + bo);
        sacc[c] = __builtin_amdgcn_mfma_f32_16x16x32_bf16(khf, qh[kc], sacc[c], 0, 0, 0);
        sacc[c] = __builtin_amdgcn_mfma_f32_16x16x32_bf16(khf, ql[kc], sacc[c], 0, 0, 0);
        sacc[c] = __builtin_amdgcn_mfma_f32_16x16x32_bf16(klf, qh[kc], sacc[c], 0, 0, 0);
      }
    }
    // ---- mask + online softmax ----
    int qloc = w * 16 + lr;
    bool diag = (kb == qt);
    float tm = -1e30f;
#pragma unroll
    for (int c = 0; c < 4; c++) {
#pragma unroll
      for (int r = 0; r < 4; r++) {
        int kvloc = c * 16 + 4 * g + r;
        bool vis = ((vm >> kvloc) & 1ull) && (!diag || kvloc <= qloc);
        float sv = vis ? sacc[c][r] : -1e30f;
        sacc[c][r] = sv;
        tm = fmaxf(tm, sv);
      }
    }
    tm = fmaxf(tm, __shfl_xor(tm, 16));
    tm = fmaxf(tm, __shfl_xor(tm, 32));
    float newm = fmaxf(m, tm);
    float alpha = __expf(m - newm);
    float rs = 0.f;
#pragma unroll
    for (int c = 0; c < 4; c++) {
#pragma unroll
      for (int r = 0; r < 4; r++) {
        float p = __expf(sacc[c][r] - newm);
        sacc[c][r] = p;
        rs += p;
      }
    }
    rs += __shfl_xor(rs, 16);
    rs += __shfl_xor(rs, 32);
    m = newm;
    l = l * alpha + rs;
#pragma unroll
    for (int dg = 0; dg < 4; dg++) {
#pragma unroll
      for (int r = 0; r < 4; r++) oacc[dg][r] *= alpha;
    }
    // ---- write P hi/lo to per-wave LDS ----
#pragma unroll
    for (int c = 0; c < 4; c++) {
      bf16x4 ph, pl2;
#pragma unroll
      for (int r = 0; r < 4; r++) {
        float pv = sacc[c][r];
        unsigned short h_ = f2bf(pv);
        ph[r] = (short)h_;
        pl2[r] = (short)f2bf(pv - bf2f(h_));
      }
      int bo = FSWZ(lr, lr * 128 + (c * 16 + 4 * g) * 2);
      *(bf16x4*)(pbase + bo) = ph;
      *(bf16x4*)(plbase + bo) = pl2;
    }
    // ---- PV: O^T += V^T * P^T ----
    bf16x8 pbh[2], pbl[2];
#pragma unroll
    for (int kc = 0; kc < 2; kc++) {
      int bo = FSWZ(lr, lr * 128 + kc * 64 + g * 16);
      pbh[kc] = *(const bf16x8*)(pbase + bo);
      pbl[kc] = *(const bf16x8*)(plbase + bo);
    }
#pragma unroll
    for (int dg = 0; dg < 4; dg++) {
#pragma unroll
      for (int kc = 0; kc < 2; kc++) {
        int row = dg * 16 + lr;
        int bo = FSWZ(row, row * 128 + kc * 64 + g * 16);
        bf16x8 vhf = *(const bf16x8*)((char*)Vhi + bo);
        bf16x8 vlf = *(const bf16x8*)((char*)Vlo + bo);
        oacc[dg] = __builtin_amdgcn_mfma_f32_16x16x32_bf16(vhf, pbh[kc], oacc[dg], 0, 0, 0);
        oacc[dg] = __builtin_amdgcn_mfma_f32_16x16x32_bf16(vhf, pbl[kc], oacc[dg], 0, 0, 0);
        oacc[dg] = __builtin_amdgcn_mfma_f32_16x16x32_bf16(vlf, pbh[kc], oacc[dg], 0, 0, 0);
      }
    }
  }

  float inv = 1.f / l;
  size_t ob = (size_t)qrow * 1024 + head * HD;
#pragma unroll
  for (int dg = 0; dg < 4; dg++) {
    bf16x4 th, tl;
#pragma unroll
    for (int r = 0; r < 4; r++) {
      float vv = oacc[dg][r] * inv;
      unsigned short h_ = f2bf(vv);
      th[r] = (short)h_;
      tl[r] = (short)f2bf(vv - bf2f(h_));
    }
    *(bf16x4*)(ohi + ob + dg * 16 + 4 * g) = th;
    *(bf16x4*)(olo + ob + dg * 16 + 4 * g) = tl;
  }
}

// ---------------- router ----------------
__global__ __launch_bounds__(256) void router_kernel(const float* __restrict__ t,
                                                     const float* __restrict__ gw,
                                                     int* __restrict__ cnt,
                                                     int* __restrict__ idxb,
                                                     float* __restrict__ wgtb) {
  int tok = blockIdx.x * 4 + (threadIdx.x >> 6);
  int lane = threadIdx.x & 63;
  const float* tr = t + (size_t)tok * H;
  float acc[NE];
#pragma unroll
  for (int e = 0; e < NE; e++) acc[e] = 0.f;
#pragma unroll
  for (int i = 0; i < 16; i++) {
    float tv = tr[lane * 16 + i];
    const float* g = gw + (size_t)(lane * 16 + i) * NE;
#pragma unroll
    for (int e = 0; e < NE; e++) acc[e] += tv * g[e];
  }
#pragma unroll
  for (int off = 1; off < 64; off <<= 1) {
#pragma unroll
    for (int e = 0; e < NE; e++) acc[e] += __shfl_xor(acc[e], off);
  }
  if (lane == 0) {
    int e1 = 0;
#pragma unroll
    for (int e = 1; e < NE; e++)
      if (acc[e] > acc[e1]) e1 = e;
    int e2 = -1;
#pragma unroll
    for (int e = 0; e < NE; e++)
      if (e != e1 && (e2 < 0 || acc[e] > acc[e2])) e2 = e;
    float w1v = 1.f / (1.f + __expf(acc[e2] - acc[e1]));
    float w2v = 1.f - w1v;
    int p1 = atomicAdd(&cnt[e1], 1);
    idxb[e1 * S + p1] = tok;
    wgtb[e1 * S + p1] = w1v;
    int p2 = atomicAdd(&cnt[e2], 1);
    idxb[e2 * S + p2] = tok;
    wgtb[e2 * S + p2] = w2v;
  }
}

// prefix offsets + dense tile table: tmap[t] = (expert<<16) | m_tile, tmap[63] = count
__global__ void offsets_kernel(const int* __restrict__ cnt, int* __restrict__ offs,
                               int* __restrict__ tmap) {
  if (threadIdx.x == 0 && blockIdx.x == 0) {
    int a = 0, t = 0;
    for (int e = 0; e < NE; e++) {
      offs[e] = a;
      a += cnt[e];
      int nt = (cnt[e] + 127) >> 7;
      for (int i = 0; i < nt; i++) tmap[t++] = (e << 16) | i;
    }
    offs[NE] = a;
    tmap[63] = t;  // t <= 40
  }
}

// ---------------- launch ----------------
extern "C" void kernel_launch(void* const* d_in, const int* in_sizes, int n_in,
                              void* d_out, int out_size, void* d_ws, size_t ws_size,
                              hipStream_t stream) {
  const float* x = (const float*)d_in[0];
  const float* amask = (const float*)d_in[1];
  const int* pos = (const int*)d_in[2];
  const float* sinb = (const float*)d_in[3];
  const float* cosb = (const float*)d_in[4];
  const float* wq = (const float*)d_in[5];
  const float* wk = (const float*)d_in[6];
  const float* wv = (const float*)d_in[7];
  const float* wo = (const float*)d_in[8];
  const float* ln1 = (const float*)d_in[9];
  const float* ln2 = (const float*)d_in[10];
  const float* gw = (const float*)d_in[11];
  const float* w1 = (const float*)d_in[12];
  const float* w3 = (const float*)d_in[13];
  const float* w2 = (const float*)d_in[14];
  float* out = (float*)d_out;

  char* ws = (char*)d_ws;
  const size_t MB = 1024 * 1024;
  // persistent
  float* x2 = (float*)(ws + 0 * MB);                    // 8 MB
  unsigned short* t_bf = (unsigned short*)(ws + 8 * MB);  // 4 MB
  int* cnt = (int*)(ws + 12 * MB);
  int* offs = cnt + 16;
  int* tmap = cnt + 32;            // 64 ints
  int* idxb = cnt + 128;
  float* wgtb = (float*)(idxb + NE * S);
  // MoE region
  unsigned short* G = (unsigned short*)(ws + 13 * MB);    // 16 MB: 13-29
  unsigned short* w1T = (unsigned short*)(ws + 29 * MB);  // 32 MB: 29-61
  unsigned short* w3T = (unsigned short*)(ws + 61 * MB);  // 32 MB: 61-93
  unsigned short* w2T = (unsigned short*)(ws + 29 * MB);  // reuse after mode2
  // phase-1 overlays (dead before MoE tconvs run)
  float* qkv = (float*)(ws + 13 * MB);                       // 16 MB: 13-29
  unsigned short* wqkvT_hi = (unsigned short*)(ws + 29 * MB);  // 4 MB
  unsigned short* wqkvT_lo = (unsigned short*)(ws + 33 * MB);  // 4 MB
  unsigned short* woT_hi = (unsigned short*)(ws + 37 * MB);    // 2 MB
  unsigned short* woT_lo = (unsigned short*)(ws + 39 * MB);    // 2 MB
  unsigned short* h_hi = (unsigned short*)(ws + 41 * MB);      // 4 MB
  unsigned short* h_lo = (unsigned short*)(ws + 45 * MB);      // 4 MB
  unsigned short* q_hi = (unsigned short*)(ws + 49 * MB);      // 4 MB
  unsigned short* q_lo = (unsigned short*)(ws + 53 * MB);      // 4 MB
  unsigned short* k_hi = (unsigned short*)(ws + 57 * MB);      // 2 MB
  unsigned short* k_lo = (unsigned short*)(ws + 59 * MB);      // 2 MB
  unsigned short* vT_hi = (unsigned short*)(ws + 61 * MB);     // 2 MB
  unsigned short* vT_lo = (unsigned short*)(ws + 63 * MB);     // 2 MB
  unsigned short* o_hi = (unsigned short*)(ws + 65 * MB);      // 4 MB
  unsigned short* o_lo = (unsigned short*)(ws + 69 * MB);      // 4 MB
  float* t = (float*)(ws + 73 * MB);                           // 8 MB: 73-81

  hipMemsetAsync(cnt, 0, 16 * sizeof(int), stream);

  // attention block
  rmsnorm_kernel<0><<<S, 256, 0, stream>>>(x, ln1, nullptr, h_hi, h_lo);
  tconv_kernel<true><<<dim3(16, 16, 1), 256, 0, stream>>>(wq, wqkvT_hi, wqkvT_lo, 1024, 1024, 0, 0);
  tconv_kernel<true><<<dim3(8, 16, 1), 256, 0, stream>>>(wk, wqkvT_hi + (size_t)1024 * 1024,
                                                         wqkvT_lo + (size_t)1024 * 1024, 1024, 512, 0, 0);
  tconv_kernel<true><<<dim3(8, 16, 1), 256, 0, stream>>>(wv, wqkvT_hi + (size_t)1536 * 1024,
                                                         wqkvT_lo + (size_t)1536 * 1024, 1024, 512, 0, 0);
  tconv_kernel<true><<<dim3(16, 16, 1), 256, 0, stream>>>(wo, woT_hi, woT_lo, 1024, 1024, 0, 0);

  gemm_kernel<0><<<dim3(32, 16, 1), 256, 0, stream>>>(h_hi, h_lo, wqkvT_hi, wqkvT_lo, qkv, nullptr,
                                                      nullptr, nullptr, nullptr, nullptr, nullptr,
                                                      nullptr, nullptr, 2048, 1024);
  rope_kernel<<<6144, 256, 0, stream>>>(qkv, sinb, cosb, pos, q_hi, q_lo, k_hi, k_lo);
  vtrans_kernel<<<dim3(32, 8), 256, 0, stream>>>(qkv, vT_hi, vT_lo);
  flash_kernel<<<dim3(32, 16), 256, 0, stream>>>(q_hi, q_lo, k_hi, k_lo, vT_hi, vT_lo, amask, o_hi,
                                                 o_lo);
  gemm_kernel<1><<<dim3(16, 16, 1), 256, 0, stream>>>(o_hi, o_lo, woT_hi, woT_lo, x2, out, nullptr,
                                                      x, nullptr, nullptr, nullptr, nullptr,
                                                      nullptr, 1024, 1024);
  // MoE block
  rmsnorm_kernel<1><<<S, 256, 0, stream>>>(x2, ln2, t, t_bf, nullptr);
  router_kernel<<<S / 4, 256, 0, stream>>>(t, gw, cnt, idxb, wgtb);
  offsets_kernel<<<1, 64, 0, stream>>>(cnt, offs, tmap);

  tconv_kernel<false><<<dim3(32, 16, 8), 256, 0, stream>>>(w1, w1T, nullptr, 1024, 2048,
                                                           (long long)1024 * 2048,
                                                           (long long)2048 * 1024);
  tconv_kernel<false><<<dim3(32, 16, 8), 256, 0, stream>>>(w3, w3T, nullptr, 1024, 2048,
                                                           (long long)1024 * 2048,
                                                           (long long)2048 * 1024);
  gemm_kernel<2><<<dim3(32, 40, 1), 256, 0, stream>>>(t_bf, nullptr, w1T, w3T, nullptr, nullptr, G,
                                                      nullptr, idxb, wgtb, cnt, offs, tmap, 2048,
                                                      1024);
  tconv_kernel<false><<<dim3(16, 32, 8), 256, 0, stream>>>(w2, w2T, nullptr, 2048, 1024,
                                                           (long long)2048 * 1024,
                                                           (long long)1024 * 2048);
  gemm_kernel<3><<<dim3(16, 40, 1), 256, 0, stream>>>(G, nullptr, w2T, nullptr, out, nullptr,
                                                      nullptr, nullptr, idxb, wgtb, cnt, offs, tmap,
                                                      1024, 2048);
}